// Round 9
// baseline (24025.604 us; speedup 1.0000x reference)
//
#include <hip/hip_runtime.h>

// ---------------- problem constants ----------------
#define B_ 8
#define S_ 128
#define H_ 512
#define G_ 2048   // 4H
#define MEL_ 80

// ---------------- ws layout (32-bit word offsets) ----------------
// decoder flags: per batch 1024 words: C lines 0..7 (slice), B line 8
#define FLG_DEC    0                    // 8 * 1024 = 8192
#define FLG_L0     8192                 // 16 groups * 128 words (8 flag lines)
#define FLG_L1     10240
#define OFF_H0S    12288                // lstm0 h [(dir*8+b)][2][512] = 16384
#define OFF_H1S    (OFF_H0S + 16384)    // 16384
#define OFF_DH     (OFF_H1S + 16384)    // dec h [2][b][512] = 8192 (ping-pong)
#define OFF_DIN    (OFF_DH + 8192)      // din [b][128] = 1024 (80 used)
#define OFF_CTX    (OFF_DIN + 1024)     // [b][1024] = 8192
#define ZERO_WORDS (OFF_CTX + 8192)     // = 62464 = 244*256
#define OFF_X0     62464                        // [bs][512]   524288
#define OFF_GX0F   (OFF_X0 + 524288)            // [bs][2048] 2097152
#define OFF_GX0B   (OFF_GX0F + 2097152)
#define OFF_H0     (OFF_GX0B + 2097152)         // [bs][1024] 1048576
#define OFF_GX1F   (OFF_H0 + 1048576)
#define OFF_GX1B   (OFF_GX1F + 2097152)
#define OFF_ENC    (OFF_GX1B + 2097152)         // [bs][1024] 1048576
#define OFF_ENCP   (OFF_ENC + 1048576)          // [bs][512]   524288

// ---------------- helpers ----------------
__device__ __forceinline__ float sigm_f(float x) {
    x = fminf(fmaxf(x, -30.f), 30.f);
    return 1.f / (1.f + __expf(-x));
}
__device__ __forceinline__ float tanh_f(float x) {
    x = fminf(fmaxf(x, -15.f), 15.f);
    float e = __expf(2.f * x);
    return (e - 1.f) / (e + 1.f);
}

// device-scope (cross-XCD safe) uncached scalar access for tiny state
__device__ __forceinline__ void agw_u(unsigned* p, unsigned v) {
    __hip_atomic_store(p, v, __ATOMIC_RELAXED, __HIP_MEMORY_SCOPE_AGENT);
}
__device__ __forceinline__ unsigned agr_u(const unsigned* p) {
    return __hip_atomic_load(p, __ATOMIC_RELAXED, __HIP_MEMORY_SCOPE_AGENT);
}
__device__ __forceinline__ void agw_f(float* p, float v) {
    agw_u((unsigned*)p, __float_as_uint(v));
}
__device__ __forceinline__ float agr_f(const float* p) {
    return __uint_as_float(agr_u((const unsigned*)p));
}

// poll nf flag lines (stride 16 words) until >= phase
__device__ __forceinline__ void poll_flags(const unsigned* flags, int nf, unsigned phase) {
    if ((int)threadIdx.x < nf) {
        while (agr_u(flags + threadIdx.x * 16) < phase)
            __builtin_amdgcn_s_sleep(1);
    }
    __syncthreads();
}

// drain own stores to coherence point, then arrive
__device__ __forceinline__ void set_flag(unsigned* flag, unsigned phase) {
    asm volatile("s_waitcnt vmcnt(0) lgkmcnt(0)" ::: "memory");
    __syncthreads();
    if (threadIdx.x == 0)
        agw_u(flag, phase);
}

// ---------------- zero init ----------------
__global__ __launch_bounds__(256) void zero_kernel(float* p) {
    p[blockIdx.x * 256 + threadIdx.x] = 0.f;
}

// ---------------- embedding ----------------
__global__ __launch_bounds__(256) void embed_kernel(const int* __restrict__ text,
                                                    const float* __restrict__ emb,
                                                    float* __restrict__ X) {
    int i = blockIdx.x * 256 + threadIdx.x;   // float4 id, 131072 total
    int bs = i >> 7;
    int h4 = i & 127;
    int ch = text[bs];
    ((float4*)X)[i] = ((const float4*)emb)[ch * 128 + h4];
}

// ---------------- f32 GEMM: C[M,N] = A[M,K] * W[N,K]^T + b1 (+ b2) ----------------
__global__ __launch_bounds__(256) void gemm_f32(const float* __restrict__ A, int lda,
                                                const float* __restrict__ W, int ldw,
                                                const float* __restrict__ b1,
                                                const float* __restrict__ b2,
                                                float* __restrict__ C, int ldc, int K) {
    __shared__ float As[32][68];
    __shared__ float Ws[32][68];
    int tid = threadIdx.x;
    int tx = tid & 15, ty = tid >> 4;
    int n0 = blockIdx.x * 64, m0 = blockIdx.y * 64;
    float acc[4][4] = {};
    int r  = tid >> 3;
    int c4 = (tid & 7) * 4;
    for (int k0 = 0; k0 < K; k0 += 32) {
        float4 a0 = *(const float4*)&A[(m0 + r) * lda + k0 + c4];
        float4 a1 = *(const float4*)&A[(m0 + r + 32) * lda + k0 + c4];
        float4 w0 = *(const float4*)&W[(n0 + r) * ldw + k0 + c4];
        float4 w1 = *(const float4*)&W[(n0 + r + 32) * ldw + k0 + c4];
        As[c4 + 0][r] = a0.x; As[c4 + 1][r] = a0.y; As[c4 + 2][r] = a0.z; As[c4 + 3][r] = a0.w;
        As[c4 + 0][r + 32] = a1.x; As[c4 + 1][r + 32] = a1.y; As[c4 + 2][r + 32] = a1.z; As[c4 + 3][r + 32] = a1.w;
        Ws[c4 + 0][r] = w0.x; Ws[c4 + 1][r] = w0.y; Ws[c4 + 2][r] = w0.z; Ws[c4 + 3][r] = w0.w;
        Ws[c4 + 0][r + 32] = w1.x; Ws[c4 + 1][r + 32] = w1.y; Ws[c4 + 2][r + 32] = w1.z; Ws[c4 + 3][r + 32] = w1.w;
        __syncthreads();
#pragma unroll 8
        for (int kk = 0; kk < 32; ++kk) {
            float4 av = *(const float4*)&As[kk][ty * 4];
            float4 wv = *(const float4*)&Ws[kk][tx * 4];
            acc[0][0] = fmaf(av.x, wv.x, acc[0][0]); acc[0][1] = fmaf(av.x, wv.y, acc[0][1]);
            acc[0][2] = fmaf(av.x, wv.z, acc[0][2]); acc[0][3] = fmaf(av.x, wv.w, acc[0][3]);
            acc[1][0] = fmaf(av.y, wv.x, acc[1][0]); acc[1][1] = fmaf(av.y, wv.y, acc[1][1]);
            acc[1][2] = fmaf(av.y, wv.z, acc[1][2]); acc[1][3] = fmaf(av.y, wv.w, acc[1][3]);
            acc[2][0] = fmaf(av.z, wv.x, acc[2][0]); acc[2][1] = fmaf(av.z, wv.y, acc[2][1]);
            acc[2][2] = fmaf(av.z, wv.z, acc[2][2]); acc[2][3] = fmaf(av.z, wv.w, acc[2][3]);
            acc[3][0] = fmaf(av.w, wv.x, acc[3][0]); acc[3][1] = fmaf(av.w, wv.y, acc[3][1]);
            acc[3][2] = fmaf(av.w, wv.z, acc[3][2]); acc[3][3] = fmaf(av.w, wv.w, acc[3][3]);
        }
        __syncthreads();
    }
#pragma unroll
    for (int i = 0; i < 4; ++i)
#pragma unroll
        for (int j = 0; j < 4; ++j) {
            int n = n0 + tx * 4 + j;
            int m = m0 + ty * 4 + i;
            float bias = b1[n] + (b2 ? b2[n] : 0.f);
            C[m * ldc + n] = acc[i][j] + bias;
        }
}

// ---------------- per-(dir,batch) LSTM, same-XCD groups ----------------
// 128 WGs: xcd = wg&7 -> dir = xcd>>2, b = ((xcd&3)<<1)|(slot>>3), slice = slot&7
// (slot = wg>>3). All 8 WGs of a (dir,b) group sit on ONE XCD; that XCD's L2
// holds the whole 4 MB Whh of its dir (shared by its 2 batch groups).
// One same-XCD rendezvous per step.
__global__ __launch_bounds__(256) void lstm_kernel(const float* __restrict__ GXf,
                                                   const float* __restrict__ GXb,
                                                   const float* __restrict__ Whh_f,
                                                   const float* __restrict__ Whh_b,
                                                   float* __restrict__ Hout,
                                                   float* __restrict__ hstate,
                                                   unsigned* __restrict__ flagsL) {
    int wg    = blockIdx.x;
    int xcd   = wg & 7;
    int slot  = wg >> 3;          // 0..15
    int slice = slot & 7;
    int dir   = xcd >> 2;
    int b     = ((xcd & 3) << 1) | (slot >> 3);
    int g16   = dir * 8 + b;
    const float* GX  = dir ? GXb : GXf;
    const float* Whh = dir ? Whh_b : Whh_f;
    float* hs = hstate + g16 * 1024;         // [2][512]
    unsigned* fg = flagsL + g16 * 128;       // 8 flag lines

    int tid = threadIdx.x;
    int g = tid >> 6, c = tid & 63;
    int col = slice * 64 + c;
    int grow = g * 512 + col;
    const float* wr = Whh + (size_t)grow * 512;

    __shared__ float hsh[512];
    __shared__ float gvL[4][64];

    float cst = 0.f;    // cell state (tid<64: col2 = slice*64+tid)

    for (int t = 0; t < 128; ++t) {
        poll_flags(fg, 8, (unsigned)t);
        hsh[tid]       = agr_f(hs + (t & 1) * 512 + tid);
        hsh[tid + 256] = agr_f(hs + (t & 1) * 512 + 256 + tid);
        __syncthreads();

        int st = dir ? (127 - t) : t;
        float acc = GX[((size_t)b * S_ + st) * G_ + grow];
        float a0 = 0.f, a1 = 0.f, a2 = 0.f, a3 = 0.f;
#pragma unroll 8
        for (int k = 0; k < 512; k += 4) {
            float4 wv = *(const float4*)(wr + k);
            float4 hv = *(const float4*)&hsh[k];
            a0 = fmaf(wv.x, hv.x, a0); a1 = fmaf(wv.y, hv.y, a1);
            a2 = fmaf(wv.z, hv.z, a2); a3 = fmaf(wv.w, hv.w, a3);
        }
        gvL[g][c] = acc + (a0 + a1) + (a2 + a3);
        __syncthreads();

        float h2 = 0.f;
        if (tid < 64) {
            float gi = gvL[0][tid], gf = gvL[1][tid];
            float gg = gvL[2][tid], go = gvL[3][tid];
            float c2 = sigm_f(gf) * cst + sigm_f(gi) * tanh_f(gg);
            h2 = sigm_f(go) * tanh_f(c2);
            cst = c2;
            agw_f(hs + ((t & 1) ^ 1) * 512 + slice * 64 + tid, h2);
        }
        set_flag(fg + slice * 16, (unsigned)(t + 1));
        // layer output: off critical path (after arrive)
        if (tid < 64)
            Hout[((size_t)b * S_ + st) * 1024 + dir * 512 + slice * 64 + tid] = h2;
    }
}

// ---------------- per-batch decoder, same-XCD groups: 72 WGs ----------------
// wg&7 = b (= XCD under round-robin); role = wg>>3: 0 = attention WG,
// 1..8 = gate slice s = role-1 (owns cols [s*64,(s+1)*64) x 4 gates = 256 rows).
// 2 same-XCD rendezvous/step:
//   C (8 flags, one per slice): h_t ready (DH ping-pong buffer t&1)
//   B (1 flag): attn finished -> DIN/CTX ready
// Gate WGs overlap hdec (Whh@h) under the attention phase.
__global__ __launch_bounds__(256) void decoder_kernel(float* __restrict__ ws,
                                                      const float* __restrict__ attn_W,
                                                      const float* __restrict__ attn_v,
                                                      const float* __restrict__ dec_Wih,
                                                      const float* __restrict__ dec_Whh,
                                                      const float* __restrict__ dec_bih,
                                                      const float* __restrict__ dec_bhh,
                                                      const float* __restrict__ mel_W,
                                                      const float* __restrict__ mel_b,
                                                      float* __restrict__ out, int T,
                                                      unsigned* __restrict__ flags) {
    float* ENC  = ws + OFF_ENC;
    float* ENCP = ws + OFF_ENCP;
    float* DH   = ws + OFF_DH;    // [2][8][512]
    float* DIN  = ws + OFF_DIN;
    float* CTX  = ws + OFF_CTX;

    int wg  = blockIdx.x;    // 0..71
    int b   = wg & 7;
    int role = wg >> 3;      // 0 attn, 1..8 gate
    int tid = threadIdx.x;

    unsigned* fC = flags + b * 1024;     // 8 lines
    unsigned* fB = fC + 8 * 16;          // 1 line

    if (role > 0) {
        // ================= gate WG (slice s) =================
        int s = role - 1;
        int g = tid >> 6, c = tid & 63;
        int grow = g * 512 + s * 64 + c;
        const float* whh_row = dec_Whh + (size_t)grow * 512;
        const float* wih_row = dec_Wih + (size_t)grow * 1104;
        float bias_r = dec_bih[grow] + dec_bhh[grow];

        __shared__ float dh[512];
        __shared__ float gvv[4][64];
        __shared__ float xin[1104];

        float cst = 0.f;    // tid<64: col = s*64+tid

        for (int t = 0; t < T; ++t) {
            // ---- phase A: h_t -> hdec (overlaps attention WG) ----
            poll_flags(fC, 8, (unsigned)t);
            const float* DHr = DH + (t & 1) * 4096 + b * 512;
            dh[tid]       = agr_f(DHr + tid);
            dh[tid + 256] = agr_f(DHr + 256 + tid);
            __syncthreads();

            float a0 = bias_r, a1 = 0.f, a2 = 0.f, a3 = 0.f;
#pragma unroll 8
            for (int k = 0; k < 512; k += 4) {
                float4 wv = *(const float4*)(whh_row + k);
                float4 hv = *(const float4*)&dh[k];
                a0 = fmaf(wv.x, hv.x, a0); a1 = fmaf(wv.y, hv.y, a1);
                a2 = fmaf(wv.z, hv.z, a2); a3 = fmaf(wv.w, hv.w, a3);
            }
            float hd = (a0 + a1) + (a2 + a3);

            // ---- phase B: gates + cell ----
            poll_flags(fB, 1, (unsigned)(t + 1));
            for (int n = tid; n < 1104; n += 256)
                xin[n] = (n < 80) ? agr_f(DIN + b * 128 + n)
                                  : agr_f(CTX + b * 1024 + (n - 80));
            __syncthreads();

            float b0 = 0.f, b1v = 0.f, b2v = 0.f, b3 = 0.f;
#pragma unroll 4
            for (int k = 0; k < 1104; k += 4) {
                float4 wv = *(const float4*)(wih_row + k);
                float4 xv = *(const float4*)&xin[k];
                b0 = fmaf(wv.x, xv.x, b0); b1v = fmaf(wv.y, xv.y, b1v);
                b2v = fmaf(wv.z, xv.z, b2v); b3 = fmaf(wv.w, xv.w, b3);
            }
            gvv[g][c] = (b0 + b1v) + (b2v + b3) + hd;
            __syncthreads();

            if (tid < 64) {
                float gi = gvv[0][tid], gf = gvv[1][tid];
                float gg = gvv[2][tid], go = gvv[3][tid];
                float c2 = sigm_f(gf) * cst + sigm_f(gi) * tanh_f(gg);
                float h2 = sigm_f(go) * tanh_f(c2);
                cst = c2;
                agw_f(DH + ((t & 1) ^ 1) * 4096 + b * 512 + s * 64 + tid, h2);
            }
            set_flag(fC + s * 16, (unsigned)(t + 1));
        }
    } else {
        // ================= attention WG (batch b) =================
        __shared__ float dh2[512];
        __shared__ float hw[512];
        __shared__ float scred[128][2];
        __shared__ float red[128];
        __shared__ float att[128];
        __shared__ float melp[80][2];

        int r = tid >> 1, half = tid & 1;

        for (int t = 0; t <= T; ++t) {
            poll_flags(fC, 8, (unsigned)t);
            const float* DHr = DH + (t & 1) * 4096 + b * 512;
            dh2[tid]       = agr_f(DHr + tid);
            dh2[tid + 256] = agr_f(DHr + 256 + tid);
            __syncthreads();

            // mel from h_t (= output frame t-1)
            if (t > 0) {
                if (tid < 160) {
                    const float* wp = mel_W + (size_t)r * 512 + half * 256;
                    const float* hp = dh2 + half * 256;
                    float a0 = 0.f, a1 = 0.f, a2 = 0.f, a3 = 0.f;
#pragma unroll 8
                    for (int k = 0; k < 256; k += 4) {
                        float4 wv = *(const float4*)(wp + k);
                        float4 hv = *(const float4*)(hp + k);
                        a0 = fmaf(wv.x, hv.x, a0); a1 = fmaf(wv.y, hv.y, a1);
                        a2 = fmaf(wv.z, hv.z, a2); a3 = fmaf(wv.w, hv.w, a3);
                    }
                    melp[r][half] = (a0 + a1) + (a2 + a3);
                }
                __syncthreads();
                if (tid < 80) {
                    float mel = melp[tid][0] + melp[tid][1] + mel_b[tid];
                    if (t < T) agw_f(DIN + b * 128 + tid, mel);
                    out[b * MEL_ * T + tid * T + (t - 1)] = mel;
                }
            }
            if (t == T) break;   // epilogue: final frame only

            // hW: rows tid, tid+256 (W_h = attn_W[:, :512], row stride 1536)
#pragma unroll
            for (int rr = 0; rr < 2; ++rr) {
                int row = tid + rr * 256;
                const float* wr = attn_W + (size_t)row * 1536;
                float a0 = 0.f, a1 = 0.f, a2 = 0.f, a3 = 0.f;
#pragma unroll 8
                for (int k = 0; k < 512; k += 4) {
                    float4 wv = *(const float4*)(wr + k);
                    float4 hv = *(const float4*)&dh2[k];
                    a0 = fmaf(wv.x, hv.x, a0); a1 = fmaf(wv.y, hv.y, a1);
                    a2 = fmaf(wv.z, hv.z, a2); a3 = fmaf(wv.w, hv.w, a3);
                }
                hw[row] = (a0 + a1) + (a2 + a3);
            }
            __syncthreads();

            // scores: sI = tid&127, k-half = tid>>7
            {
                int sI = tid & 127, kh = tid >> 7;
                const float* ep = ENCP + ((size_t)b * S_ + sI) * 512 + kh * 256;
                const float* hp = hw + kh * 256;
                const float* vv = attn_v + kh * 256;
                float a0 = 0.f, a1 = 0.f, a2 = 0.f, a3 = 0.f;
#pragma unroll 4
                for (int k = 0; k < 256; k += 4) {
                    float4 e4 = *(const float4*)(ep + k);
                    float4 h4 = *(const float4*)(hp + k);
                    float4 v4 = *(const float4*)(vv + k);
                    a0 = fmaf(tanh_f(e4.x + h4.x), v4.x, a0);
                    a1 = fmaf(tanh_f(e4.y + h4.y), v4.y, a1);
                    a2 = fmaf(tanh_f(e4.z + h4.z), v4.z, a2);
                    a3 = fmaf(tanh_f(e4.w + h4.w), v4.w, a3);
                }
                scred[sI][kh] = (a0 + a1) + (a2 + a3);
            }
            __syncthreads();

            float sc = 0.f;
            if (tid < 128) {
                sc = scred[tid][0] + scred[tid][1];
                red[tid] = sc;
            }
            __syncthreads();
            for (int off = 64; off >= 1; off >>= 1) {
                if (tid < off) red[tid] = fmaxf(red[tid], red[tid + off]);
                __syncthreads();
            }
            float mx = red[0];
            __syncthreads();
            if (tid < 128) {
                float e = __expf(sc - mx);
                att[tid] = e;
                red[tid] = e;
            }
            __syncthreads();
            if (tid < 64) red[tid] += red[tid + 64];
            __syncthreads();
            for (int off = 32; off >= 1; off >>= 1) {
                if (tid < off) red[tid] += red[tid + off];
                __syncthreads();
            }
            float inv = 1.f / red[0];

            // ctx: 4 cols/thread (coalesced float4 rows of ENC)
            {
                int d = tid * 4;
                const float* ebase = ENC + (size_t)b * S_ * 1024 + d;
                float c0 = 0.f, c1 = 0.f, c2 = 0.f, c3 = 0.f;
#pragma unroll 4
                for (int s2 = 0; s2 < 128; ++s2) {
                    float a = att[s2];
                    float4 ev = *(const float4*)(ebase + (size_t)s2 * 1024);
                    c0 = fmaf(a, ev.x, c0); c1 = fmaf(a, ev.y, c1);
                    c2 = fmaf(a, ev.z, c2); c3 = fmaf(a, ev.w, c3);
                }
                agw_f(CTX + b * 1024 + d,     c0 * inv);
                agw_f(CTX + b * 1024 + d + 1, c1 * inv);
                agw_f(CTX + b * 1024 + d + 2, c2 * inv);
                agw_f(CTX + b * 1024 + d + 3, c3 * inv);
            }
            set_flag(fB, (unsigned)(t + 1));
        }
    }
}

// ---------------- host launch ----------------
extern "C" void kernel_launch(void* const* d_in, const int* in_sizes, int n_in,
                              void* d_out, int out_size, void* d_ws, size_t ws_size,
                              hipStream_t stream) {
    const int*   text  = (const int*)d_in[0];
    const float* emb   = (const float*)d_in[2];
    const float* Wih00 = (const float*)d_in[3];
    const float* Whh00 = (const float*)d_in[4];
    const float* bih00 = (const float*)d_in[5];
    const float* bhh00 = (const float*)d_in[6];
    const float* Wih01 = (const float*)d_in[7];
    const float* Whh01 = (const float*)d_in[8];
    const float* bih01 = (const float*)d_in[9];
    const float* bhh01 = (const float*)d_in[10];
    const float* Wih10 = (const float*)d_in[11];
    const float* Whh10 = (const float*)d_in[12];
    const float* bih10 = (const float*)d_in[13];
    const float* bhh10 = (const float*)d_in[14];
    const float* Wih11 = (const float*)d_in[15];
    const float* Whh11 = (const float*)d_in[16];
    const float* bih11 = (const float*)d_in[17];
    const float* bhh11 = (const float*)d_in[18];
    const float* attn_W = (const float*)d_in[19];
    const float* attn_b = (const float*)d_in[20];
    const float* attn_v = (const float*)d_in[21];
    const float* dec_Wih = (const float*)d_in[22];
    const float* dec_Whh = (const float*)d_in[23];
    const float* dec_bih = (const float*)d_in[24];
    const float* dec_bhh = (const float*)d_in[25];
    const float* mel_W = (const float*)d_in[26];
    const float* mel_b = (const float*)d_in[27];

    float* ws = (float*)d_ws;
    unsigned* flags = (unsigned*)d_ws;
    float* out = (float*)d_out;
    int T = out_size / (B_ * MEL_);   // 200

    // zero flags + recurrent state
    zero_kernel<<<ZERO_WORDS / 256, 256, 0, stream>>>(ws);

    // embedding
    embed_kernel<<<512, 256, 0, stream>>>(text, emb, ws + OFF_X0);

    // layer0 input projections (bias folded: bih + bhh)
    gemm_f32<<<dim3(32, 16), 256, 0, stream>>>(ws + OFF_X0, 512, Wih00, 512,
                                               bih00, bhh00, ws + OFF_GX0F, 2048, 512);
    gemm_f32<<<dim3(32, 16), 256, 0, stream>>>(ws + OFF_X0, 512, Wih01, 512,
                                               bih01, bhh01, ws + OFF_GX0B, 2048, 512);
    // layer0 recurrence: 16 same-XCD (dir,b) groups x 8 slice WGs
    lstm_kernel<<<128, 256, 0, stream>>>(ws + OFF_GX0F, ws + OFF_GX0B, Whh00, Whh01,
                                         ws + OFF_H0, ws + OFF_H0S, flags + FLG_L0);
    // layer1 input projections
    gemm_f32<<<dim3(32, 16), 256, 0, stream>>>(ws + OFF_H0, 1024, Wih10, 1024,
                                               bih10, bhh10, ws + OFF_GX1F, 2048, 1024);
    gemm_f32<<<dim3(32, 16), 256, 0, stream>>>(ws + OFF_H0, 1024, Wih11, 1024,
                                               bih11, bhh11, ws + OFF_GX1B, 2048, 1024);
    // layer1 recurrence -> enc
    lstm_kernel<<<128, 256, 0, stream>>>(ws + OFF_GX1F, ws + OFF_GX1B, Whh10, Whh11,
                                         ws + OFF_ENC, ws + OFF_H1S, flags + FLG_L1);
    // enc_part = enc @ W_e^T + attn_b   (W_e = attn_W[:, 512:], row stride 1536)
    gemm_f32<<<dim3(8, 16), 256, 0, stream>>>(ws + OFF_ENC, 1024, attn_W + 512, 1536,
                                              attn_b, nullptr, ws + OFF_ENCP, 512, 1024);
    // decoder: 8 same-XCD batch groups (1 attn WG + 8 gate WGs each)
    decoder_kernel<<<72, 256, 0, stream>>>(ws, attn_W, attn_v, dec_Wih, dec_Whh,
                                           dec_bih, dec_bhh, mel_W, mel_b, out, T,
                                           flags + FLG_DEC);
}

// Round 10
// 20181.212 us; speedup vs baseline: 1.1905x; 1.1905x over previous
//
#include <hip/hip_runtime.h>

// ---------------- problem constants ----------------
#define B_ 8
#define S_ 128
#define H_ 512
#define G_ 2048   // 4H
#define MEL_ 80

// ---------------- ws layout (32-bit word offsets) ----------------
// decoder flags: per batch 1024 words: C lines 0..15 (slice), B line 16
#define FLG_DEC    0                    // 8 * 1024 = 8192
#define FLG_L0     8192                 // 16 groups * 128 words (8 flag lines)
#define FLG_L1     10240
#define OFF_H0S    12288                // lstm0 h [(dir*8+b)][2][512] = 16384
#define OFF_H1S    (OFF_H0S + 16384)    // 16384
#define OFF_DH     (OFF_H1S + 16384)    // dec h [2][b][512] = 8192 (ping-pong)
#define OFF_DIN    (OFF_DH + 8192)      // din [b][128] = 1024 (80 used)
#define OFF_CTX    (OFF_DIN + 1024)     // [b][1024] = 8192
#define ZERO_WORDS (OFF_CTX + 8192)     // = 62464 = 244*256
#define OFF_X0     62464                        // [bs][512]   524288
#define OFF_GX0F   (OFF_X0 + 524288)            // [bs][2048] 2097152
#define OFF_GX0B   (OFF_GX0F + 2097152)
#define OFF_H0     (OFF_GX0B + 2097152)         // [bs][1024] 1048576
#define OFF_GX1F   (OFF_H0 + 1048576)
#define OFF_GX1B   (OFF_GX1F + 2097152)
#define OFF_ENC    (OFF_GX1B + 2097152)         // [bs][1024] 1048576
#define OFF_ENCP   (OFF_ENC + 1048576)          // [bs][512]   524288

// ---------------- helpers ----------------
__device__ __forceinline__ float sigm_f(float x) {
    x = fminf(fmaxf(x, -30.f), 30.f);
    return 1.f / (1.f + __expf(-x));
}
__device__ __forceinline__ float tanh_f(float x) {
    x = fminf(fmaxf(x, -15.f), 15.f);
    float e = __expf(2.f * x);
    return (e - 1.f) / (e + 1.f);
}

// device-scope uncached scalar access for tiny cross-WG state.
// Crucial property (r8 lesson): bypasses caches WITHOUT invalidating them,
// so L2-resident weights stay hot.
__device__ __forceinline__ void agw_u(unsigned* p, unsigned v) {
    __hip_atomic_store(p, v, __ATOMIC_RELAXED, __HIP_MEMORY_SCOPE_AGENT);
}
__device__ __forceinline__ unsigned agr_u(const unsigned* p) {
    return __hip_atomic_load(p, __ATOMIC_RELAXED, __HIP_MEMORY_SCOPE_AGENT);
}
__device__ __forceinline__ void agw_f(float* p, float v) {
    agw_u((unsigned*)p, __float_as_uint(v));
}
__device__ __forceinline__ float agr_f(const float* p) {
    return __uint_as_float(agr_u((const unsigned*)p));
}

// poll nf flag lines (stride 16 words) until >= phase
__device__ __forceinline__ void poll_flags(const unsigned* flags, int nf, unsigned phase) {
    if ((int)threadIdx.x < nf) {
        while (agr_u(flags + threadIdx.x * 16) < phase)
            __builtin_amdgcn_s_sleep(1);
    }
    __syncthreads();
}

// drain own stores to coherence point, then arrive
__device__ __forceinline__ void set_flag(unsigned* flag, unsigned phase) {
    asm volatile("s_waitcnt vmcnt(0) lgkmcnt(0)" ::: "memory");
    __syncthreads();
    if (threadIdx.x == 0)
        agw_u(flag, phase);
}

// ---------------- zero init ----------------
__global__ __launch_bounds__(256) void zero_kernel(float* p) {
    p[blockIdx.x * 256 + threadIdx.x] = 0.f;
}

// ---------------- embedding ----------------
__global__ __launch_bounds__(256) void embed_kernel(const int* __restrict__ text,
                                                    const float* __restrict__ emb,
                                                    float* __restrict__ X) {
    int i = blockIdx.x * 256 + threadIdx.x;   // float4 id, 131072 total
    int bs = i >> 7;
    int h4 = i & 127;
    int ch = text[bs];
    ((float4*)X)[i] = ((const float4*)emb)[ch * 128 + h4];
}

// ---------------- f32 GEMM: C[M,N] = A[M,K] * W[N,K]^T + b1 (+ b2) ----------------
__global__ __launch_bounds__(256) void gemm_f32(const float* __restrict__ A, int lda,
                                                const float* __restrict__ W, int ldw,
                                                const float* __restrict__ b1,
                                                const float* __restrict__ b2,
                                                float* __restrict__ C, int ldc, int K) {
    __shared__ float As[32][68];
    __shared__ float Ws[32][68];
    int tid = threadIdx.x;
    int tx = tid & 15, ty = tid >> 4;
    int n0 = blockIdx.x * 64, m0 = blockIdx.y * 64;
    float acc[4][4] = {};
    int r  = tid >> 3;
    int c4 = (tid & 7) * 4;
    for (int k0 = 0; k0 < K; k0 += 32) {
        float4 a0 = *(const float4*)&A[(m0 + r) * lda + k0 + c4];
        float4 a1 = *(const float4*)&A[(m0 + r + 32) * lda + k0 + c4];
        float4 w0 = *(const float4*)&W[(n0 + r) * ldw + k0 + c4];
        float4 w1 = *(const float4*)&W[(n0 + r + 32) * ldw + k0 + c4];
        As[c4 + 0][r] = a0.x; As[c4 + 1][r] = a0.y; As[c4 + 2][r] = a0.z; As[c4 + 3][r] = a0.w;
        As[c4 + 0][r + 32] = a1.x; As[c4 + 1][r + 32] = a1.y; As[c4 + 2][r + 32] = a1.z; As[c4 + 3][r + 32] = a1.w;
        Ws[c4 + 0][r] = w0.x; Ws[c4 + 1][r] = w0.y; Ws[c4 + 2][r] = w0.z; Ws[c4 + 3][r] = w0.w;
        Ws[c4 + 0][r + 32] = w1.x; Ws[c4 + 1][r + 32] = w1.y; Ws[c4 + 2][r + 32] = w1.z; Ws[c4 + 3][r + 32] = w1.w;
        __syncthreads();
#pragma unroll 8
        for (int kk = 0; kk < 32; ++kk) {
            float4 av = *(const float4*)&As[kk][ty * 4];
            float4 wv = *(const float4*)&Ws[kk][tx * 4];
            acc[0][0] = fmaf(av.x, wv.x, acc[0][0]); acc[0][1] = fmaf(av.x, wv.y, acc[0][1]);
            acc[0][2] = fmaf(av.x, wv.z, acc[0][2]); acc[0][3] = fmaf(av.x, wv.w, acc[0][3]);
            acc[1][0] = fmaf(av.y, wv.x, acc[1][0]); acc[1][1] = fmaf(av.y, wv.y, acc[1][1]);
            acc[1][2] = fmaf(av.y, wv.z, acc[1][2]); acc[1][3] = fmaf(av.y, wv.w, acc[1][3]);
            acc[2][0] = fmaf(av.z, wv.x, acc[2][0]); acc[2][1] = fmaf(av.z, wv.y, acc[2][1]);
            acc[2][2] = fmaf(av.z, wv.z, acc[2][2]); acc[2][3] = fmaf(av.z, wv.w, acc[2][3]);
            acc[3][0] = fmaf(av.w, wv.x, acc[3][0]); acc[3][1] = fmaf(av.w, wv.y, acc[3][1]);
            acc[3][2] = fmaf(av.w, wv.z, acc[3][2]); acc[3][3] = fmaf(av.w, wv.w, acc[3][3]);
        }
        __syncthreads();
    }
#pragma unroll
    for (int i = 0; i < 4; ++i)
#pragma unroll
        for (int j = 0; j < 4; ++j) {
            int n = n0 + tx * 4 + j;
            int m = m0 + ty * 4 + i;
            float bias = b1[n] + (b2 ? b2[n] : 0.f);
            C[m * ldc + n] = acc[i][j] + bias;
        }
}

// ---------------- per-(dir,batch) LSTM: slice-major (r8, best) ----------------
// 128 WGs: wg = s + 8*g16 (s = slice 0..7 -> XCD s; g16 = dir*8 + b).
// XCD s's L2 caches slice-s Whh rows of BOTH dirs (1 MB), shared by 16 groups.
// One rendezvous per step (own group's 8 C-flags).
__global__ __launch_bounds__(256) void lstm_kernel(const float* __restrict__ GXf,
                                                   const float* __restrict__ GXb,
                                                   const float* __restrict__ Whh_f,
                                                   const float* __restrict__ Whh_b,
                                                   float* __restrict__ Hout,
                                                   float* __restrict__ hstate,
                                                   unsigned* __restrict__ flagsL) {
    int wg  = blockIdx.x;
    int s   = wg & 7;
    int g16 = wg >> 3;        // 0..15
    int dir = g16 >> 3;
    int b   = g16 & 7;
    const float* GX  = dir ? GXb : GXf;
    const float* Whh = dir ? Whh_b : Whh_f;
    float* hs = hstate + g16 * 1024;         // [2][512]
    unsigned* fg = flagsL + g16 * 128;       // 8 flag lines

    int tid = threadIdx.x;
    int g = tid >> 6, c = tid & 63;
    int col = s * 64 + c;
    int grow = g * 512 + col;
    const float* wr = Whh + (size_t)grow * 512;

    __shared__ float hsh[512];
    __shared__ float gvL[4][64];

    float cst = 0.f;    // cell state (tid<64: col = s*64+tid)

    for (int t = 0; t < 128; ++t) {
        poll_flags(fg, 8, (unsigned)t);
        hsh[tid]       = agr_f(hs + (t & 1) * 512 + tid);
        hsh[tid + 256] = agr_f(hs + (t & 1) * 512 + 256 + tid);
        __syncthreads();

        int st = dir ? (127 - t) : t;
        float acc = GX[((size_t)b * S_ + st) * G_ + grow];
        float a0 = 0.f, a1 = 0.f, a2 = 0.f, a3 = 0.f;
#pragma unroll 8
        for (int k = 0; k < 512; k += 4) {
            float4 wv = *(const float4*)(wr + k);
            float4 hv = *(const float4*)&hsh[k];
            a0 = fmaf(wv.x, hv.x, a0); a1 = fmaf(wv.y, hv.y, a1);
            a2 = fmaf(wv.z, hv.z, a2); a3 = fmaf(wv.w, hv.w, a3);
        }
        gvL[g][c] = acc + (a0 + a1) + (a2 + a3);
        __syncthreads();

        float h2 = 0.f;
        if (tid < 64) {
            float gi = gvL[0][tid], gf = gvL[1][tid];
            float gg = gvL[2][tid], go = gvL[3][tid];
            float c2 = sigm_f(gf) * cst + sigm_f(gi) * tanh_f(gg);
            h2 = sigm_f(go) * tanh_f(c2);
            cst = c2;
            agw_f(hs + ((t & 1) ^ 1) * 512 + s * 64 + tid, h2);
        }
        set_flag(fg + s * 16, (unsigned)(t + 1));
        // layer output: off critical path (after arrive)
        if (tid < 64)
            Hout[((size_t)b * S_ + st) * 1024 + dir * 512 + s * 64 + tid] = h2;
    }
}

// ---------------- decoder: slice-major gates + per-batch attention ----------------
// 136 WGs. gate WG: wg = b*16 + s (s = 0..15) -> XCD s%8: slice s (128 rows:
// cols [s*32,(s+1)*32) x 4 gates) shared by all 8 batches on that XCD -> L2-hot.
// attn WG: wg = 128+b -> XCD b: W_h(1MB)+mel_W(160KB)+ENC/ENCP_b(768KB) L2-hot.
// Per-XCD: 2x821KB slices + 1.93MB attn = 3.57MB < 4MB.
// 2 rendezvous/step: C (16 slice flags: h_t ready, DH ping-pong) and
// B (1 flag: DIN/CTX ready). hdec overlaps the attention phase.
__global__ __launch_bounds__(256) void decoder_kernel(float* __restrict__ ws,
                                                      const float* __restrict__ attn_W,
                                                      const float* __restrict__ attn_v,
                                                      const float* __restrict__ dec_Wih,
                                                      const float* __restrict__ dec_Whh,
                                                      const float* __restrict__ dec_bih,
                                                      const float* __restrict__ dec_bhh,
                                                      const float* __restrict__ mel_W,
                                                      const float* __restrict__ mel_b,
                                                      float* __restrict__ out, int T,
                                                      unsigned* __restrict__ flags) {
    float* ENC  = ws + OFF_ENC;
    float* ENCP = ws + OFF_ENCP;
    float* DH   = ws + OFF_DH;    // [2][8][512]
    float* DIN  = ws + OFF_DIN;
    float* CTX  = ws + OFF_CTX;

    int wg  = blockIdx.x;    // 0..135
    int tid = threadIdx.x;

    if (wg < 128) {
        // ================= gate WG (slice s, batch b) =================
        int s = wg & 15;
        int b = wg >> 4;
        unsigned* fC = flags + b * 1024;     // 16 lines
        unsigned* fB = fC + 16 * 16;         // line 16

        int r = tid >> 1, half = tid & 1;    // 128 rows x 2 k-halves
        int grow = (r >> 5) * 512 + s * 32 + (r & 31);
        const float* whh_half = dec_Whh + (size_t)grow * 512 + half * 256;
        const float* wih_half = dec_Wih + (size_t)grow * 1104 + half * 552;
        float bias_r = (half == 0) ? (dec_bih[grow] + dec_bhh[grow]) : 0.f;

        __shared__ float dh[512];
        __shared__ float gBx[128][2];
        __shared__ float gv[128];
        __shared__ float xin[1104];

        float cst = 0.f;    // tid<32: col = s*32+tid

        for (int t = 0; t < T; ++t) {
            // ---- stage h_t, hdec partial (overlaps attention WG) ----
            poll_flags(fC, 16, (unsigned)t);
            const float* DHr = DH + (t & 1) * 4096 + b * 512;
            dh[tid]       = agr_f(DHr + tid);
            dh[tid + 256] = agr_f(DHr + 256 + tid);
            __syncthreads();

            float hd;
            {
                const float* hp = dh + half * 256;
                float a0 = bias_r, a1 = 0.f, a2 = 0.f, a3 = 0.f;
#pragma unroll 8
                for (int k = 0; k < 256; k += 4) {
                    float4 wv = *(const float4*)(whh_half + k);
                    float4 hv = *(const float4*)(hp + k);
                    a0 = fmaf(wv.x, hv.x, a0); a1 = fmaf(wv.y, hv.y, a1);
                    a2 = fmaf(wv.z, hv.z, a2); a3 = fmaf(wv.w, hv.w, a3);
                }
                hd = (a0 + a1) + (a2 + a3);
            }

            // ---- gates + cell ----
            poll_flags(fB, 1, (unsigned)(t + 1));
            for (int n = tid; n < 1104; n += 256)
                xin[n] = (n < 80) ? agr_f(DIN + b * 128 + n)
                                  : agr_f(CTX + b * 1024 + (n - 80));
            __syncthreads();
            {
                const float* xp = xin + half * 552;
                float a0 = 0.f, a1 = 0.f, a2 = 0.f, a3 = 0.f;
#pragma unroll 8
                for (int k = 0; k < 552; k += 4) {
                    float4 wv = *(const float4*)(wih_half + k);
                    float4 xv = *(const float4*)(xp + k);
                    a0 = fmaf(wv.x, xv.x, a0); a1 = fmaf(wv.y, xv.y, a1);
                    a2 = fmaf(wv.z, xv.z, a2); a3 = fmaf(wv.w, xv.w, a3);
                }
                gBx[r][half] = (a0 + a1) + (a2 + a3) + hd;
            }
            __syncthreads();
            if (tid < 128)
                gv[tid] = gBx[tid][0] + gBx[tid][1];
            __syncthreads();
            if (tid < 32) {
                float gi = gv[tid], gf = gv[32 + tid];
                float gg = gv[64 + tid], go = gv[96 + tid];
                float c2 = sigm_f(gf) * cst + sigm_f(gi) * tanh_f(gg);
                float h2 = sigm_f(go) * tanh_f(c2);
                cst = c2;
                agw_f(DH + ((t & 1) ^ 1) * 4096 + b * 512 + s * 32 + tid, h2);
            }
            set_flag(fC + s * 16, (unsigned)(t + 1));
        }
    } else {
        // ================= attention WG (batch b) =================
        int b = wg - 128;
        unsigned* fC = flags + b * 1024;
        unsigned* fB = fC + 16 * 16;

        __shared__ float dh2[512];
        __shared__ float hw[512];
        __shared__ float scred[128][2];
        __shared__ float red[128];
        __shared__ float att[128];
        __shared__ float melp[80][2];

        int r = tid >> 1, half = tid & 1;

        for (int t = 0; t <= T; ++t) {
            poll_flags(fC, 16, (unsigned)t);
            const float* DHr = DH + (t & 1) * 4096 + b * 512;
            dh2[tid]       = agr_f(DHr + tid);
            dh2[tid + 256] = agr_f(DHr + 256 + tid);
            __syncthreads();

            // mel from h_t (= output frame t-1); din for this step's gates
            float melv = 0.f;
            if (t > 0) {
                if (tid < 160) {
                    const float* wp = mel_W + (size_t)r * 512 + half * 256;
                    const float* hp = dh2 + half * 256;
                    float a0 = 0.f, a1 = 0.f, a2 = 0.f, a3 = 0.f;
#pragma unroll 8
                    for (int k = 0; k < 256; k += 4) {
                        float4 wv = *(const float4*)(wp + k);
                        float4 hv = *(const float4*)(hp + k);
                        a0 = fmaf(wv.x, hv.x, a0); a1 = fmaf(wv.y, hv.y, a1);
                        a2 = fmaf(wv.z, hv.z, a2); a3 = fmaf(wv.w, hv.w, a3);
                    }
                    melp[r][half] = (a0 + a1) + (a2 + a3);
                }
                __syncthreads();
                if (tid < 80) {
                    melv = melp[tid][0] + melp[tid][1] + mel_b[tid];
                    if (t < T) agw_f(DIN + b * 128 + tid, melv);
                }
            }
            if (t == T) {
                if (tid < 80) out[b * MEL_ * T + tid * T + (T - 1)] = melv;
                break;
            }

            // hW: rows tid, tid+256 (W_h = attn_W[:, :512], row stride 1536;
            // dh2[k] is a broadcast read -> conflict-free)
#pragma unroll
            for (int rr = 0; rr < 2; ++rr) {
                int row = tid + rr * 256;
                const float* wr = attn_W + (size_t)row * 1536;
                float a0 = 0.f, a1 = 0.f, a2 = 0.f, a3 = 0.f;
#pragma unroll 8
                for (int k = 0; k < 512; k += 4) {
                    float4 wv = *(const float4*)(wr + k);
                    float4 hv = *(const float4*)&dh2[k];
                    a0 = fmaf(wv.x, hv.x, a0); a1 = fmaf(wv.y, hv.y, a1);
                    a2 = fmaf(wv.z, hv.z, a2); a3 = fmaf(wv.w, hv.w, a3);
                }
                hw[row] = (a0 + a1) + (a2 + a3);
            }
            __syncthreads();

            // scores: sI = tid&127, k-half = tid>>7
            {
                int sI = tid & 127, kh = tid >> 7;
                const float* ep = ENCP + ((size_t)b * S_ + sI) * 512 + kh * 256;
                const float* hp = hw + kh * 256;
                const float* vv = attn_v + kh * 256;
                float a0 = 0.f, a1 = 0.f, a2 = 0.f, a3 = 0.f;
#pragma unroll 4
                for (int k = 0; k < 256; k += 4) {
                    float4 e4 = *(const float4*)(ep + k);
                    float4 h4 = *(const float4*)(hp + k);
                    float4 v4 = *(const float4*)(vv + k);
                    a0 = fmaf(tanh_f(e4.x + h4.x), v4.x, a0);
                    a1 = fmaf(tanh_f(e4.y + h4.y), v4.y, a1);
                    a2 = fmaf(tanh_f(e4.z + h4.z), v4.z, a2);
                    a3 = fmaf(tanh_f(e4.w + h4.w), v4.w, a3);
                }
                scred[sI][kh] = (a0 + a1) + (a2 + a3);
            }
            __syncthreads();

            float sc = 0.f;
            if (tid < 128) {
                sc = scred[tid][0] + scred[tid][1];
                red[tid] = sc;
            }
            __syncthreads();
            for (int off = 64; off >= 1; off >>= 1) {
                if (tid < off) red[tid] = fmaxf(red[tid], red[tid + off]);
                __syncthreads();
            }
            float mx = red[0];
            __syncthreads();
            if (tid < 128) {
                float e = __expf(sc - mx);
                att[tid] = e;
                red[tid] = e;
            }
            __syncthreads();
            if (tid < 64) red[tid] += red[tid + 64];
            __syncthreads();
            for (int off = 32; off >= 1; off >>= 1) {
                if (tid < off) red[tid] += red[tid + off];
                __syncthreads();
            }
            float inv = 1.f / red[0];

            // ctx: 4 cols/thread (coalesced float4 rows of ENC)
            {
                int d = tid * 4;
                const float* ebase = ENC + (size_t)b * S_ * 1024 + d;
                float c0 = 0.f, c1 = 0.f, c2 = 0.f, c3 = 0.f;
#pragma unroll 4
                for (int s2 = 0; s2 < 128; ++s2) {
                    float a = att[s2];
                    float4 ev = *(const float4*)(ebase + (size_t)s2 * 1024);
                    c0 = fmaf(a, ev.x, c0); c1 = fmaf(a, ev.y, c1);
                    c2 = fmaf(a, ev.z, c2); c3 = fmaf(a, ev.w, c3);
                }
                agw_f(CTX + b * 1024 + d,     c0 * inv);
                agw_f(CTX + b * 1024 + d + 1, c1 * inv);
                agw_f(CTX + b * 1024 + d + 2, c2 * inv);
                agw_f(CTX + b * 1024 + d + 3, c3 * inv);
            }
            set_flag(fB, (unsigned)(t + 1));
            // out store after the flag -> off the critical path
            if (t > 0 && tid < 80)
                out[b * MEL_ * T + tid * T + (t - 1)] = melv;
        }
    }
}

// ---------------- host launch ----------------
extern "C" void kernel_launch(void* const* d_in, const int* in_sizes, int n_in,
                              void* d_out, int out_size, void* d_ws, size_t ws_size,
                              hipStream_t stream) {
    const int*   text  = (const int*)d_in[0];
    const float* emb   = (const float*)d_in[2];
    const float* Wih00 = (const float*)d_in[3];
    const float* Whh00 = (const float*)d_in[4];
    const float* bih00 = (const float*)d_in[5];
    const float* bhh00 = (const float*)d_in[6];
    const float* Wih01 = (const float*)d_in[7];
    const float* Whh01 = (const float*)d_in[8];
    const float* bih01 = (const float*)d_in[9];
    const float* bhh01 = (const float*)d_in[10];
    const float* Wih10 = (const float*)d_in[11];
    const float* Whh10 = (const float*)d_in[12];
    const float* bih10 = (const float*)d_in[13];
    const float* bhh10 = (const float*)d_in[14];
    const float* Wih11 = (const float*)d_in[15];
    const float* Whh11 = (const float*)d_in[16];
    const float* bih11 = (const float*)d_in[17];
    const float* bhh11 = (const float*)d_in[18];
    const float* attn_W = (const float*)d_in[19];
    const float* attn_b = (const float*)d_in[20];
    const float* attn_v = (const float*)d_in[21];
    const float* dec_Wih = (const float*)d_in[22];
    const float* dec_Whh = (const float*)d_in[23];
    const float* dec_bih = (const float*)d_in[24];
    const float* dec_bhh = (const float*)d_in[25];
    const float* mel_W = (const float*)d_in[26];
    const float* mel_b = (const float*)d_in[27];

    float* ws = (float*)d_ws;
    unsigned* flags = (unsigned*)d_ws;
    float* out = (float*)d_out;
    int T = out_size / (B_ * MEL_);   // 200

    // zero flags + recurrent state
    zero_kernel<<<ZERO_WORDS / 256, 256, 0, stream>>>(ws);

    // embedding
    embed_kernel<<<512, 256, 0, stream>>>(text, emb, ws + OFF_X0);

    // layer0 input projections (bias folded: bih + bhh)
    gemm_f32<<<dim3(32, 16), 256, 0, stream>>>(ws + OFF_X0, 512, Wih00, 512,
                                               bih00, bhh00, ws + OFF_GX0F, 2048, 512);
    gemm_f32<<<dim3(32, 16), 256, 0, stream>>>(ws + OFF_X0, 512, Wih01, 512,
                                               bih01, bhh01, ws + OFF_GX0B, 2048, 512);
    // layer0 recurrence: slice-major (r8)
    lstm_kernel<<<128, 256, 0, stream>>>(ws + OFF_GX0F, ws + OFF_GX0B, Whh00, Whh01,
                                         ws + OFF_H0, ws + OFF_H0S, flags + FLG_L0);
    // layer1 input projections
    gemm_f32<<<dim3(32, 16), 256, 0, stream>>>(ws + OFF_H0, 1024, Wih10, 1024,
                                               bih10, bhh10, ws + OFF_GX1F, 2048, 1024);
    gemm_f32<<<dim3(32, 16), 256, 0, stream>>>(ws + OFF_H0, 1024, Wih11, 1024,
                                               bih11, bhh11, ws + OFF_GX1B, 2048, 1024);
    // layer1 recurrence -> enc
    lstm_kernel<<<128, 256, 0, stream>>>(ws + OFF_GX1F, ws + OFF_GX1B, Whh10, Whh11,
                                         ws + OFF_ENC, ws + OFF_H1S, flags + FLG_L1);
    // enc_part = enc @ W_e^T + attn_b   (W_e = attn_W[:, 512:], row stride 1536)
    gemm_f32<<<dim3(8, 16), 256, 0, stream>>>(ws + OFF_ENC, 1024, attn_W + 512, 1536,
                                              attn_b, nullptr, ws + OFF_ENCP, 512, 1024);
    // decoder: 128 slice-major gate WGs + 8 attention WGs, 2 rendezvous/step
    decoder_kernel<<<136, 256, 0, stream>>>(ws, attn_W, attn_v, dec_Wih, dec_Whh,
                                            dec_bih, dec_bhh, mel_W, mel_b, out, T,
                                            flags + FLG_DEC);
}

// Round 11
// 14138.464 us; speedup vs baseline: 1.6993x; 1.4274x over previous
//
#include <hip/hip_runtime.h>

// ---------------- problem constants ----------------
#define B_ 8
#define S_ 128
#define H_ 512
#define G_ 2048   // 4H
#define MEL_ 80

// ---------------- ws layout (32-bit word offsets) ----------------
// decoder flags: per batch 1024 words: C lines 0..15, A lines 16..31, B line 32
#define FLG_DEC    0                    // 8 * 1024 = 8192
#define FLG_L0     8192                 // 16 groups * 128 words (8 flag lines)
#define FLG_L1     10240
#define OFF_H0S    12288                // lstm0 h [(dir*8+b)][2][512] = 16384
#define OFF_H1S    (OFF_H0S + 16384)    // 16384
#define OFF_DH     (OFF_H1S + 16384)    // dec h [b][512] = 4096
#define OFF_DIN    (OFF_DH + 4096)      // din [b][128] = 1024 (80 used)
#define OFF_HW     (OFF_DIN + 1024)     // [b][512] = 4096
#define OFF_CTX    (OFF_HW + 4096)      // [b][1024] = 8192
#define ZERO_WORDS (OFF_CTX + 8192)     // = 62464 = 244*256
#define OFF_X0     62464                        // [bs][512]   524288
#define OFF_GX0F   (OFF_X0 + 524288)            // [bs][2048] 2097152
#define OFF_GX0B   (OFF_GX0F + 2097152)
#define OFF_H0     (OFF_GX0B + 2097152)         // [bs][1024] 1048576
#define OFF_GX1F   (OFF_H0 + 1048576)
#define OFF_GX1B   (OFF_GX1F + 2097152)
#define OFF_ENC    (OFF_GX1B + 2097152)         // [bs][1024] 1048576
#define OFF_ENCP   (OFF_ENC + 1048576)          // [bs][512]   524288

// ---------------- helpers ----------------
__device__ __forceinline__ float sigm_f(float x) {
    x = fminf(fmaxf(x, -30.f), 30.f);
    return 1.f / (1.f + __expf(-x));
}
__device__ __forceinline__ float tanh_f(float x) {
    x = fminf(fmaxf(x, -15.f), 15.f);
    float e = __expf(2.f * x);
    return (e - 1.f) / (e + 1.f);
}

// device-scope uncached scalar access for tiny cross-WG state.
// Bypasses caches WITHOUT invalidating them -> L2-resident weights stay hot.
__device__ __forceinline__ void agw_u(unsigned* p, unsigned v) {
    __hip_atomic_store(p, v, __ATOMIC_RELAXED, __HIP_MEMORY_SCOPE_AGENT);
}
__device__ __forceinline__ unsigned agr_u(const unsigned* p) {
    return __hip_atomic_load(p, __ATOMIC_RELAXED, __HIP_MEMORY_SCOPE_AGENT);
}
__device__ __forceinline__ void agw_f(float* p, float v) {
    agw_u((unsigned*)p, __float_as_uint(v));
}
__device__ __forceinline__ float agr_f(const float* p) {
    return __uint_as_float(agr_u((const unsigned*)p));
}

// poll nf flag lines (stride 16 words) until >= phase
__device__ __forceinline__ void poll_flags(const unsigned* flags, int nf, unsigned phase) {
    if ((int)threadIdx.x < nf) {
        while (agr_u(flags + threadIdx.x * 16) < phase)
            __builtin_amdgcn_s_sleep(1);
    }
    __syncthreads();
}

// drain own stores to coherence point, then arrive
__device__ __forceinline__ void set_flag(unsigned* flag, unsigned phase) {
    asm volatile("s_waitcnt vmcnt(0) lgkmcnt(0)" ::: "memory");
    __syncthreads();
    if (threadIdx.x == 0)
        agw_u(flag, phase);
}

// ---------------- zero init ----------------
__global__ __launch_bounds__(256) void zero_kernel(float* p) {
    p[blockIdx.x * 256 + threadIdx.x] = 0.f;
}

// ---------------- embedding ----------------
__global__ __launch_bounds__(256) void embed_kernel(const int* __restrict__ text,
                                                    const float* __restrict__ emb,
                                                    float* __restrict__ X) {
    int i = blockIdx.x * 256 + threadIdx.x;   // float4 id, 131072 total
    int bs = i >> 7;
    int h4 = i & 127;
    int ch = text[bs];
    ((float4*)X)[i] = ((const float4*)emb)[ch * 128 + h4];
}

// ---------------- f32 GEMM: C[M,N] = A[M,K] * W[N,K]^T + b1 (+ b2) ----------------
__global__ __launch_bounds__(256) void gemm_f32(const float* __restrict__ A, int lda,
                                                const float* __restrict__ W, int ldw,
                                                const float* __restrict__ b1,
                                                const float* __restrict__ b2,
                                                float* __restrict__ C, int ldc, int K) {
    __shared__ float As[32][68];
    __shared__ float Ws[32][68];
    int tid = threadIdx.x;
    int tx = tid & 15, ty = tid >> 4;
    int n0 = blockIdx.x * 64, m0 = blockIdx.y * 64;
    float acc[4][4] = {};
    int r  = tid >> 3;
    int c4 = (tid & 7) * 4;
    for (int k0 = 0; k0 < K; k0 += 32) {
        float4 a0 = *(const float4*)&A[(m0 + r) * lda + k0 + c4];
        float4 a1 = *(const float4*)&A[(m0 + r + 32) * lda + k0 + c4];
        float4 w0 = *(const float4*)&W[(n0 + r) * ldw + k0 + c4];
        float4 w1 = *(const float4*)&W[(n0 + r + 32) * ldw + k0 + c4];
        As[c4 + 0][r] = a0.x; As[c4 + 1][r] = a0.y; As[c4 + 2][r] = a0.z; As[c4 + 3][r] = a0.w;
        As[c4 + 0][r + 32] = a1.x; As[c4 + 1][r + 32] = a1.y; As[c4 + 2][r + 32] = a1.z; As[c4 + 3][r + 32] = a1.w;
        Ws[c4 + 0][r] = w0.x; Ws[c4 + 1][r] = w0.y; Ws[c4 + 2][r] = w0.z; Ws[c4 + 3][r] = w0.w;
        Ws[c4 + 0][r + 32] = w1.x; Ws[c4 + 1][r + 32] = w1.y; Ws[c4 + 2][r + 32] = w1.z; Ws[c4 + 3][r + 32] = w1.w;
        __syncthreads();
#pragma unroll 8
        for (int kk = 0; kk < 32; ++kk) {
            float4 av = *(const float4*)&As[kk][ty * 4];
            float4 wv = *(const float4*)&Ws[kk][tx * 4];
            acc[0][0] = fmaf(av.x, wv.x, acc[0][0]); acc[0][1] = fmaf(av.x, wv.y, acc[0][1]);
            acc[0][2] = fmaf(av.x, wv.z, acc[0][2]); acc[0][3] = fmaf(av.x, wv.w, acc[0][3]);
            acc[1][0] = fmaf(av.y, wv.x, acc[1][0]); acc[1][1] = fmaf(av.y, wv.y, acc[1][1]);
            acc[1][2] = fmaf(av.y, wv.z, acc[1][2]); acc[1][3] = fmaf(av.y, wv.w, acc[1][3]);
            acc[2][0] = fmaf(av.z, wv.x, acc[2][0]); acc[2][1] = fmaf(av.z, wv.y, acc[2][1]);
            acc[2][2] = fmaf(av.z, wv.z, acc[2][2]); acc[2][3] = fmaf(av.z, wv.w, acc[2][3]);
            acc[3][0] = fmaf(av.w, wv.x, acc[3][0]); acc[3][1] = fmaf(av.w, wv.y, acc[3][1]);
            acc[3][2] = fmaf(av.w, wv.z, acc[3][2]); acc[3][3] = fmaf(av.w, wv.w, acc[3][3]);
        }
        __syncthreads();
    }
#pragma unroll
    for (int i = 0; i < 4; ++i)
#pragma unroll
        for (int j = 0; j < 4; ++j) {
            int n = n0 + tx * 4 + j;
            int m = m0 + ty * 4 + i;
            float bias = b1[n] + (b2 ? b2[n] : 0.f);
            C[m * ldc + n] = acc[i][j] + bias;
        }
}

// ---------------- per-(dir,batch) LSTM: slice-major (r8, best) ----------------
// 128 WGs: wg = s + 8*g16 (s = slice 0..7 -> XCD s; g16 = dir*8 + b).
// XCD s's L2 caches slice-s Whh rows of BOTH dirs (1 MB), shared by 16 groups.
// One rendezvous per step (own group's 8 C-flags).
__global__ __launch_bounds__(256) void lstm_kernel(const float* __restrict__ GXf,
                                                   const float* __restrict__ GXb,
                                                   const float* __restrict__ Whh_f,
                                                   const float* __restrict__ Whh_b,
                                                   float* __restrict__ Hout,
                                                   float* __restrict__ hstate,
                                                   unsigned* __restrict__ flagsL) {
    int wg  = blockIdx.x;
    int s   = wg & 7;
    int g16 = wg >> 3;        // 0..15
    int dir = g16 >> 3;
    int b   = g16 & 7;
    const float* GX  = dir ? GXb : GXf;
    const float* Whh = dir ? Whh_b : Whh_f;
    float* hs = hstate + g16 * 1024;         // [2][512]
    unsigned* fg = flagsL + g16 * 128;       // 8 flag lines

    int tid = threadIdx.x;
    int g = tid >> 6, c = tid & 63;
    int col = s * 64 + c;
    int grow = g * 512 + col;
    const float* wr = Whh + (size_t)grow * 512;

    __shared__ float hsh[512];
    __shared__ float gvL[4][64];

    float cst = 0.f;    // cell state (tid<64: col = s*64+tid)

    for (int t = 0; t < 128; ++t) {
        poll_flags(fg, 8, (unsigned)t);
        hsh[tid]       = agr_f(hs + (t & 1) * 512 + tid);
        hsh[tid + 256] = agr_f(hs + (t & 1) * 512 + 256 + tid);
        __syncthreads();

        int st = dir ? (127 - t) : t;
        float acc = GX[((size_t)b * S_ + st) * G_ + grow];
        float a0 = 0.f, a1 = 0.f, a2 = 0.f, a3 = 0.f;
#pragma unroll 8
        for (int k = 0; k < 512; k += 4) {
            float4 wv = *(const float4*)(wr + k);
            float4 hv = *(const float4*)&hsh[k];
            a0 = fmaf(wv.x, hv.x, a0); a1 = fmaf(wv.y, hv.y, a1);
            a2 = fmaf(wv.z, hv.z, a2); a3 = fmaf(wv.w, hv.w, a3);
        }
        gvL[g][c] = acc + (a0 + a1) + (a2 + a3);
        __syncthreads();

        float h2 = 0.f;
        if (tid < 64) {
            float gi = gvL[0][tid], gf = gvL[1][tid];
            float gg = gvL[2][tid], go = gvL[3][tid];
            float c2 = sigm_f(gf) * cst + sigm_f(gi) * tanh_f(gg);
            h2 = sigm_f(go) * tanh_f(c2);
            cst = c2;
            agw_f(hs + ((t & 1) ^ 1) * 512 + s * 64 + tid, h2);
        }
        set_flag(fg + s * 16, (unsigned)(t + 1));
        // layer output: off critical path (after arrive)
        if (tid < 64)
            Hout[((size_t)b * S_ + st) * 1024 + dir * 512 + s * 64 + tid] = h2;
    }
}

// ---------------- per-batch decoder: 136 WGs (r8 structure) ----------------
// gate WG: wg = b*16 + s -> XCD s%8: slice s (128 rows: cols [s*32,(s+1)*32)
// x 4 gates) shared by all 8 batches on that XCD -> L2-hot; also computes the
// hW rows [s*32,(s+1)*32) (W_h slice, 192KB/XCD).
// attn WG: wg = 128+b -> XCD b: mel + scores + softmax + ctx (ENC/ENCP_b +
// mel_W L2-hot, ~930KB). Per-XCD total ~2.8 MB < effective L2 (~3 MB).
// 3 edges/step: C (16 slice flags: h_t ready) -> A (16 flags: hW ready) ->
// B (1 flag: DIN/CTX ready).
// Bank-conflict fix vs r8: hW gather uses r2 = tid&31 / oct = tid>>5 so all
// 32 lanes of a half-wave read ONE broadcast LDS address (r8's oct = tid&7
// put all 8 octs at bank 0 -> 8-way serialize, 7.5e7 conflicts); partial
// buffer padded [32][9] (9 coprime 32 -> conflict-free writes).
__global__ __launch_bounds__(256) void decoder_kernel(float* __restrict__ ws,
                                                      const float* __restrict__ attn_W,
                                                      const float* __restrict__ attn_v,
                                                      const float* __restrict__ dec_Wih,
                                                      const float* __restrict__ dec_Whh,
                                                      const float* __restrict__ dec_bih,
                                                      const float* __restrict__ dec_bhh,
                                                      const float* __restrict__ mel_W,
                                                      const float* __restrict__ mel_b,
                                                      float* __restrict__ out, int T,
                                                      unsigned* __restrict__ flags) {
    float* ENC  = ws + OFF_ENC;
    float* ENCP = ws + OFF_ENCP;
    float* DH   = ws + OFF_DH;
    float* DIN  = ws + OFF_DIN;
    float* HW   = ws + OFF_HW;
    float* CTX  = ws + OFF_CTX;

    int wg  = blockIdx.x;
    int tid = threadIdx.x;

    if (wg < 128) {
        // ================= gate WG (slice s, batch b) =================
        int s = wg & 15;
        int b = wg >> 4;
        unsigned* fC = flags + b * 1024;
        unsigned* fA = fC + 16 * 16;
        unsigned* fB = fC + 32 * 16;

        int r   = tid >> 1;                 // local row 0..127
        int half = tid & 1;
        int grow = (r >> 5) * 512 + s * 32 + (r & 31);
        const float* whh_half = dec_Whh + (size_t)grow * 512 + half * 256;
        const float* wih_half = dec_Wih + (size_t)grow * 1104 + half * 552;
        float bias_r = (half == 0) ? (dec_bih[grow] + dec_bhh[grow]) : 0.f;
        // hW mapping (conflict-free): r2 = tid&31 (row), oct = tid>>5 (k-oct)
        int r2 = tid & 31, oct = tid >> 5;
        const float* wh_row = attn_W + (size_t)(s * 32 + r2) * 1536 + oct * 64;

        __shared__ float hsh[512];
        __shared__ float hdL[128][2];
        __shared__ float hwred[32][9];      // padded: 9 coprime 32
        __shared__ float gBx[128][2];
        __shared__ float gv[128];
        __shared__ float xin[1104];

        float cst = 0.f;   // threads tid<32: col = s*32+tid

        for (int t = 0; t < T; ++t) {
            // ---- phase A: stage h_t; hdec partial; hW slice ----
            poll_flags(fC, 16, (unsigned)t);
            hsh[tid]       = agr_f(DH + b * 512 + tid);
            hsh[tid + 256] = agr_f(DH + b * 512 + 256 + tid);
            __syncthreads();
            // hdec partial (own half of k)
            {
                const float* hp = hsh + half * 256;
                float a0 = 0.f, a1 = 0.f, a2 = 0.f, a3 = 0.f;
#pragma unroll 8
                for (int k = 0; k < 256; k += 4) {
                    float4 wv = *(const float4*)(whh_half + k);
                    float4 hv = *(const float4*)(hp + k);
                    a0 = fmaf(wv.x, hv.x, a0); a1 = fmaf(wv.y, hv.y, a1);
                    a2 = fmaf(wv.z, hv.z, a2); a3 = fmaf(wv.w, hv.w, a3);
                }
                hdL[r][half] = (a0 + a1) + (a2 + a3) + bias_r;
            }
            // hW slice: rows s*32..s*32+31 (broadcast LDS reads: 32 lanes
            // share one address per k-iter -> conflict-free)
            {
                const float* hp = hsh + oct * 64;
                float w = 0.f;
#pragma unroll 8
                for (int k = 0; k < 64; k += 4) {
                    float4 wv = *(const float4*)(wh_row + k);
                    float4 hv = *(const float4*)(hp + k);
                    w = fmaf(wv.x, hv.x, w); w = fmaf(wv.y, hv.y, w);
                    w = fmaf(wv.z, hv.z, w); w = fmaf(wv.w, hv.w, w);
                }
                hwred[r2][oct] = w;
            }
            __syncthreads();
            if (tid < 32) {
                float hw = hwred[tid][0] + hwred[tid][1] + hwred[tid][2] + hwred[tid][3]
                         + hwred[tid][4] + hwred[tid][5] + hwred[tid][6] + hwred[tid][7];
                agw_f(HW + b * 512 + s * 32 + tid, hw);
            }
            set_flag(fA + s * 16, (unsigned)(t + 1));

            // ---- phase B: gates + cell ----
            poll_flags(fB, 1, (unsigned)(t + 1));
            for (int n = tid; n < 1104; n += 256)
                xin[n] = (n < 80) ? agr_f(DIN + b * 128 + n)
                                  : agr_f(CTX + b * 1024 + (n - 80));
            __syncthreads();
            {
                const float* xp = xin + half * 552;
                float a0 = 0.f, a1 = 0.f, a2 = 0.f, a3 = 0.f;
#pragma unroll 8
                for (int k = 0; k < 552; k += 4) {
                    float4 wv = *(const float4*)(wih_half + k);
                    float4 xv = *(const float4*)(xp + k);
                    a0 = fmaf(wv.x, xv.x, a0); a1 = fmaf(wv.y, xv.y, a1);
                    a2 = fmaf(wv.z, xv.z, a2); a3 = fmaf(wv.w, xv.w, a3);
                }
                gBx[r][half] = (a0 + a1) + (a2 + a3);
            }
            __syncthreads();
            if (tid < 128)
                gv[tid] = gBx[tid][0] + gBx[tid][1] + hdL[tid][0] + hdL[tid][1];
            __syncthreads();
            if (tid < 32) {
                float gi = gv[tid], gf = gv[32 + tid], gg = gv[64 + tid], go = gv[96 + tid];
                float c2 = sigm_f(gf) * cst + sigm_f(gi) * tanh_f(gg);
                float h2 = sigm_f(go) * tanh_f(c2);
                cst = c2;
                agw_f(DH + b * 512 + s * 32 + tid, h2);
            }
            set_flag(fC + s * 16, (unsigned)(t + 1));
        }
    } else {
        // ================= attention WG (batch b) =================
        int b = wg - 128;
        unsigned* fC = flags + b * 1024;
        unsigned* fA = fC + 16 * 16;
        unsigned* fB = fC + 32 * 16;

        __shared__ float hsh[512];
        __shared__ float hw2[512];
        __shared__ float scred[128][2];
        __shared__ float red[128];
        __shared__ float att[128];
        __shared__ float melp[80][2];

        int r = tid >> 1, half = tid & 1;

        for (int t = 0; t < T; ++t) {
            poll_flags(fC, 16, (unsigned)t);
            hsh[tid]       = agr_f(DH + b * 512 + tid);
            hsh[tid + 256] = agr_f(DH + b * 512 + 256 + tid);
            __syncthreads();

            // mel from h (= h2 of step t-1) -> din_t; out store deferred
            float melv = 0.f;
            if (t > 0) {
                if (tid < 160) {
                    const float* wp = mel_W + (size_t)r * 512 + half * 256;
                    const float* hp = hsh + half * 256;
                    float a0 = 0.f, a1 = 0.f, a2 = 0.f, a3 = 0.f;
#pragma unroll 8
                    for (int k = 0; k < 256; k += 4) {
                        float4 wv = *(const float4*)(wp + k);
                        float4 hv = *(const float4*)(hp + k);
                        a0 = fmaf(wv.x, hv.x, a0); a1 = fmaf(wv.y, hv.y, a1);
                        a2 = fmaf(wv.z, hv.z, a2); a3 = fmaf(wv.w, hv.w, a3);
                    }
                    melp[r][half] = (a0 + a1) + (a2 + a3);
                }
                __syncthreads();
                if (tid < 80) {
                    melv = melp[tid][0] + melp[tid][1] + mel_b[tid];
                    agw_f(DIN + b * 128 + tid, melv);
                }
            }

            poll_flags(fA, 16, (unsigned)(t + 1));
            hw2[tid]       = agr_f(HW + b * 512 + tid);
            hw2[tid + 256] = agr_f(HW + b * 512 + 256 + tid);
            __syncthreads();

            // scores: sI = r-index tid&127, k-half = tid>>7
            {
                int sI = tid & 127, kh = tid >> 7;
                const float* ep = ENCP + ((size_t)b * S_ + sI) * 512 + kh * 256;
                const float* hp = hw2 + kh * 256;
                const float* vv = attn_v + kh * 256;
                float a0 = 0.f, a1 = 0.f, a2 = 0.f, a3 = 0.f;
#pragma unroll 4
                for (int k = 0; k < 256; k += 4) {
                    float4 e4 = *(const float4*)(ep + k);
                    float4 h4 = *(const float4*)(hp + k);
                    float4 v4 = *(const float4*)(vv + k);
                    a0 = fmaf(tanh_f(e4.x + h4.x), v4.x, a0);
                    a1 = fmaf(tanh_f(e4.y + h4.y), v4.y, a1);
                    a2 = fmaf(tanh_f(e4.z + h4.z), v4.z, a2);
                    a3 = fmaf(tanh_f(e4.w + h4.w), v4.w, a3);
                }
                scred[sI][kh] = (a0 + a1) + (a2 + a3);
            }
            __syncthreads();

            float sc = 0.f;
            if (tid < 128) {
                sc = scred[tid][0] + scred[tid][1];
                red[tid] = sc;
            }
            __syncthreads();
            for (int off = 64; off >= 1; off >>= 1) {
                if (tid < off) red[tid] = fmaxf(red[tid], red[tid + off]);
                __syncthreads();
            }
            float mx = red[0];
            __syncthreads();
            if (tid < 128) {
                float e = __expf(sc - mx);
                att[tid] = e;
                red[tid] = e;
            }
            __syncthreads();
            if (tid < 64) red[tid] += red[tid + 64];
            __syncthreads();
            for (int off = 32; off >= 1; off >>= 1) {
                if (tid < off) red[tid] += red[tid + off];
                __syncthreads();
            }
            float inv = 1.f / red[0];

            // ctx: 4 cols/thread (coalesced float4 rows of ENC)
            {
                int d = tid * 4;
                const float* ebase = ENC + (size_t)b * S_ * 1024 + d;
                float c0 = 0.f, c1 = 0.f, c2 = 0.f, c3 = 0.f;
#pragma unroll 4
                for (int s2 = 0; s2 < 128; ++s2) {
                    float a = att[s2];
                    float4 ev = *(const float4*)(ebase + (size_t)s2 * 1024);
                    c0 = fmaf(a, ev.x, c0); c1 = fmaf(a, ev.y, c1);
                    c2 = fmaf(a, ev.z, c2); c3 = fmaf(a, ev.w, c3);
                }
                agw_f(CTX + b * 1024 + d,     c0 * inv);
                agw_f(CTX + b * 1024 + d + 1, c1 * inv);
                agw_f(CTX + b * 1024 + d + 2, c2 * inv);
                agw_f(CTX + b * 1024 + d + 3, c3 * inv);
            }
            set_flag(fB, (unsigned)(t + 1));
            // out store after the flag -> off the critical path
            if (t > 0 && tid < 80)
                out[b * MEL_ * T + tid * T + (t - 1)] = melv;
        }

        // epilogue: final mel from final h -> out[T-1]
        poll_flags(fC, 16, (unsigned)T);
        hsh[tid]       = agr_f(DH + b * 512 + tid);
        hsh[tid + 256] = agr_f(DH + b * 512 + 256 + tid);
        __syncthreads();
        if (tid < 160) {
            const float* wp = mel_W + (size_t)r * 512 + half * 256;
            const float* hp = hsh + half * 256;
            float a0 = 0.f, a1 = 0.f, a2 = 0.f, a3 = 0.f;
#pragma unroll 8
            for (int k = 0; k < 256; k += 4) {
                float4 wv = *(const float4*)(wp + k);
                float4 hv = *(const float4*)(hp + k);
                a0 = fmaf(wv.x, hv.x, a0); a1 = fmaf(wv.y, hv.y, a1);
                a2 = fmaf(wv.z, hv.z, a2); a3 = fmaf(wv.w, hv.w, a3);
            }
            melp[r][half] = (a0 + a1) + (a2 + a3);
        }
        __syncthreads();
        if (tid < 80)
            out[b * MEL_ * T + tid * T + (T - 1)] = melp[tid][0] + melp[tid][1] + mel_b[tid];
    }
}

// ---------------- host launch ----------------
extern "C" void kernel_launch(void* const* d_in, const int* in_sizes, int n_in,
                              void* d_out, int out_size, void* d_ws, size_t ws_size,
                              hipStream_t stream) {
    const int*   text  = (const int*)d_in[0];
    const float* emb   = (const float*)d_in[2];
    const float* Wih00 = (const float*)d_in[3];
    const float* Whh00 = (const float*)d_in[4];
    const float* bih00 = (const float*)d_in[5];
    const float* bhh00 = (const float*)d_in[6];
    const float* Wih01 = (const float*)d_in[7];
    const float* Whh01 = (const float*)d_in[8];
    const float* bih01 = (const float*)d_in[9];
    const float* bhh01 = (const float*)d_in[10];
    const float* Wih10 = (const float*)d_in[11];
    const float* Whh10 = (const float*)d_in[12];
    const float* bih10 = (const float*)d_in[13];
    const float* bhh10 = (const float*)d_in[14];
    const float* Wih11 = (const float*)d_in[15];
    const float* Whh11 = (const float*)d_in[16];
    const float* bih11 = (const float*)d_in[17];
    const float* bhh11 = (const float*)d_in[18];
    const float* attn_W = (const float*)d_in[19];
    const float* attn_b = (const float*)d_in[20];
    const float* attn_v = (const float*)d_in[21];
    const float* dec_Wih = (const float*)d_in[22];
    const float* dec_Whh = (const float*)d_in[23];
    const float* dec_bih = (const float*)d_in[24];
    const float* dec_bhh = (const float*)d_in[25];
    const float* mel_W = (const float*)d_in[26];
    const float* mel_b = (const float*)d_in[27];

    float* ws = (float*)d_ws;
    unsigned* flags = (unsigned*)d_ws;
    float* out = (float*)d_out;
    int T = out_size / (B_ * MEL_);   // 200

    // zero flags + recurrent state
    zero_kernel<<<ZERO_WORDS / 256, 256, 0, stream>>>(ws);

    // embedding
    embed_kernel<<<512, 256, 0, stream>>>(text, emb, ws + OFF_X0);

    // layer0 input projections (bias folded: bih + bhh)
    gemm_f32<<<dim3(32, 16), 256, 0, stream>>>(ws + OFF_X0, 512, Wih00, 512,
                                               bih00, bhh00, ws + OFF_GX0F, 2048, 512);
    gemm_f32<<<dim3(32, 16), 256, 0, stream>>>(ws + OFF_X0, 512, Wih01, 512,
                                               bih01, bhh01, ws + OFF_GX0B, 2048, 512);
    // layer0 recurrence: slice-major (r8)
    lstm_kernel<<<128, 256, 0, stream>>>(ws + OFF_GX0F, ws + OFF_GX0B, Whh00, Whh01,
                                         ws + OFF_H0, ws + OFF_H0S, flags + FLG_L0);
    // layer1 input projections
    gemm_f32<<<dim3(32, 16), 256, 0, stream>>>(ws + OFF_H0, 1024, Wih10, 1024,
                                               bih10, bhh10, ws + OFF_GX1F, 2048, 1024);
    gemm_f32<<<dim3(32, 16), 256, 0, stream>>>(ws + OFF_H0, 1024, Wih11, 1024,
                                               bih11, bhh11, ws + OFF_GX1B, 2048, 1024);
    // layer1 recurrence -> enc
    lstm_kernel<<<128, 256, 0, stream>>>(ws + OFF_GX1F, ws + OFF_GX1B, Whh10, Whh11,
                                         ws + OFF_ENC, ws + OFF_H1S, flags + FLG_L1);
    // enc_part = enc @ W_e^T + attn_b   (W_e = attn_W[:, 512:], row stride 1536)
    gemm_f32<<<dim3(8, 16), 256, 0, stream>>>(ws + OFF_ENC, 1024, attn_W + 512, 1536,
                                              attn_b, nullptr, ws + OFF_ENCP, 512, 1024);
    // decoder: r8 structure (16 gate slices x 8 batches + 8 attn WGs)
    decoder_kernel<<<136, 256, 0, stream>>>(ws, attn_W, attn_v, dec_Wih, dec_Whh,
                                            dec_bih, dec_bhh, mel_W, mel_b, out, T,
                                            flags + FLG_DEC);
}

// Round 12
// 9865.471 us; speedup vs baseline: 2.4353x; 1.4331x over previous
//
#include <hip/hip_runtime.h>

// ---------------- problem constants ----------------
#define B_ 8
#define S_ 128
#define H_ 512
#define G_ 2048   // 4H
#define MEL_ 80

// ---------------- ws layout (32-bit word offsets) ----------------
// decoder flags per batch (1024 words): C lines 0..15, A lines 16..31, B line 32
#define FLG_DEC    0                    // 8 * 1024 = 8192
#define FLG_L0     8192                 // 16 groups * 128 words
#define FLG_L1     10240
#define OFF_H0S    12288                // lstm0 h [(dir*8+b)][2][512] = 16384
#define OFF_H1S    28672                // 16384
#define OFF_DH     45056                // dec h [2][b][512] = 8192 (ping-pong)
#define OFF_ATT    53248                // att [b][128] = 1024
#define OFF_HW     54272                // [b][512] = 4096
#define ZERO_WORDS 58368                // = 228*256
#define OFF_X0     58368                        // [bs][512]   524288
#define OFF_GX0F   (OFF_X0 + 524288)            // [bs][2048] 2097152  (-> WE after lstm1)
#define OFF_GX0B   (OFF_GX0F + 2097152)         // (-> WH2 + biases after lstm0)
#define OFF_H0     (OFF_GX0B + 2097152)         // [bs][1024] 1048576
#define OFF_GX1F   (OFF_H0 + 1048576)
#define OFF_GX1B   (OFF_GX1F + 2097152)
#define OFF_ENC    (OFF_GX1B + 2097152)         // [bs][1024] 1048576
#define OFF_ENCP   (OFF_ENC + 1048576)          // [bs][512]   524288
// precomputed regions (reuse dead GX0 buffers)
#define OFF_WE     OFF_GX0F                     // [b][2048][128] = 2097152
#define OFF_WH2    OFF_GX0B                     // [2048][512] = 1048576
#define OFF_BA     (OFF_GX0B + 1048576)         // 2048
#define OFF_BB     (OFF_GX0B + 1050624)         // 2048

// ---------------- helpers ----------------
__device__ __forceinline__ float sigm_f(float x) {
    x = fminf(fmaxf(x, -30.f), 30.f);
    return 1.f / (1.f + __expf(-x));
}
__device__ __forceinline__ float tanh_f(float x) {
    x = fminf(fmaxf(x, -15.f), 15.f);
    float e = __expf(2.f * x);
    return (e - 1.f) / (e + 1.f);
}

// device-scope uncached scalar access (bypasses caches w/o invalidating them)
__device__ __forceinline__ void agw_u(unsigned* p, unsigned v) {
    __hip_atomic_store(p, v, __ATOMIC_RELAXED, __HIP_MEMORY_SCOPE_AGENT);
}
__device__ __forceinline__ unsigned agr_u(const unsigned* p) {
    return __hip_atomic_load(p, __ATOMIC_RELAXED, __HIP_MEMORY_SCOPE_AGENT);
}
__device__ __forceinline__ void agw_f(float* p, float v) {
    agw_u((unsigned*)p, __float_as_uint(v));
}
__device__ __forceinline__ float agr_f(const float* p) {
    return __uint_as_float(agr_u((const unsigned*)p));
}

// device-coherent VECTOR load: 16B analog of the agent-scope atomic load
// (sc1 = device scope on gfx950 flat/global) -> 4x fewer coherence-point
// transactions than 4B atomics when staging cross-WG state.
__device__ __forceinline__ float4 agr_f4(const float* p) {
    float4 v;
    asm volatile("global_load_dwordx4 %0, %1, off sc1\n\t"
                 "s_waitcnt vmcnt(0)"
                 : "=v"(v) : "v"(p) : "memory");
    return v;
}

// poll nf flag lines (stride 16 words) until >= phase
__device__ __forceinline__ void poll_flags(const unsigned* flags, int nf, unsigned phase) {
    if ((int)threadIdx.x < nf) {
        while (agr_u(flags + threadIdx.x * 16) < phase)
            __builtin_amdgcn_s_sleep(1);
    }
    __syncthreads();
}

// drain own stores to coherence point, then arrive
__device__ __forceinline__ void set_flag(unsigned* flag, unsigned phase) {
    asm volatile("s_waitcnt vmcnt(0) lgkmcnt(0)" ::: "memory");
    __syncthreads();
    if (threadIdx.x == 0)
        agw_u(flag, phase);
}

// ---------------- zero init ----------------
__global__ __launch_bounds__(256) void zero_kernel(float* p) {
    p[blockIdx.x * 256 + threadIdx.x] = 0.f;
}

// ---------------- embedding ----------------
__global__ __launch_bounds__(256) void embed_kernel(const int* __restrict__ text,
                                                    const float* __restrict__ emb,
                                                    float* __restrict__ X) {
    int i = blockIdx.x * 256 + threadIdx.x;   // float4 id, 131072 total
    int bs = i >> 7;
    int h4 = i & 127;
    int ch = text[bs];
    ((float4*)X)[i] = ((const float4*)emb)[ch * 128 + h4];
}

// ---------------- f32 GEMM: C[M,N] = A[M,K] * W[N,K]^T + b1 (+ b2) ----------------
__global__ __launch_bounds__(256) void gemm_f32(const float* __restrict__ A, int lda,
                                                const float* __restrict__ W, int ldw,
                                                const float* __restrict__ b1,
                                                const float* __restrict__ b2,
                                                float* __restrict__ C, int ldc, int K) {
    __shared__ float As[32][68];
    __shared__ float Ws[32][68];
    int tid = threadIdx.x;
    int tx = tid & 15, ty = tid >> 4;
    int n0 = blockIdx.x * 64, m0 = blockIdx.y * 64;
    float acc[4][4] = {};
    int r  = tid >> 3;
    int c4 = (tid & 7) * 4;
    for (int k0 = 0; k0 < K; k0 += 32) {
        float4 a0 = *(const float4*)&A[(m0 + r) * lda + k0 + c4];
        float4 a1 = *(const float4*)&A[(m0 + r + 32) * lda + k0 + c4];
        float4 w0 = *(const float4*)&W[(n0 + r) * ldw + k0 + c4];
        float4 w1 = *(const float4*)&W[(n0 + r + 32) * ldw + k0 + c4];
        As[c4 + 0][r] = a0.x; As[c4 + 1][r] = a0.y; As[c4 + 2][r] = a0.z; As[c4 + 3][r] = a0.w;
        As[c4 + 0][r + 32] = a1.x; As[c4 + 1][r + 32] = a1.y; As[c4 + 2][r + 32] = a1.z; As[c4 + 3][r + 32] = a1.w;
        Ws[c4 + 0][r] = w0.x; Ws[c4 + 1][r] = w0.y; Ws[c4 + 2][r] = w0.z; Ws[c4 + 3][r] = w0.w;
        Ws[c4 + 0][r + 32] = w1.x; Ws[c4 + 1][r + 32] = w1.y; Ws[c4 + 2][r + 32] = w1.z; Ws[c4 + 3][r + 32] = w1.w;
        __syncthreads();
#pragma unroll 8
        for (int kk = 0; kk < 32; ++kk) {
            float4 av = *(const float4*)&As[kk][ty * 4];
            float4 wv = *(const float4*)&Ws[kk][tx * 4];
            acc[0][0] = fmaf(av.x, wv.x, acc[0][0]); acc[0][1] = fmaf(av.x, wv.y, acc[0][1]);
            acc[0][2] = fmaf(av.x, wv.z, acc[0][2]); acc[0][3] = fmaf(av.x, wv.w, acc[0][3]);
            acc[1][0] = fmaf(av.y, wv.x, acc[1][0]); acc[1][1] = fmaf(av.y, wv.y, acc[1][1]);
            acc[1][2] = fmaf(av.y, wv.z, acc[1][2]); acc[1][3] = fmaf(av.y, wv.w, acc[1][3]);
            acc[2][0] = fmaf(av.z, wv.x, acc[2][0]); acc[2][1] = fmaf(av.z, wv.y, acc[2][1]);
            acc[2][2] = fmaf(av.z, wv.z, acc[2][2]); acc[2][3] = fmaf(av.z, wv.w, acc[2][3]);
            acc[3][0] = fmaf(av.w, wv.x, acc[3][0]); acc[3][1] = fmaf(av.w, wv.y, acc[3][1]);
            acc[3][2] = fmaf(av.w, wv.z, acc[3][2]); acc[3][3] = fmaf(av.w, wv.w, acc[3][3]);
        }
        __syncthreads();
    }
#pragma unroll
    for (int i = 0; i < 4; ++i)
#pragma unroll
        for (int j = 0; j < 4; ++j) {
            int n = n0 + tx * 4 + j;
            int m = m0 + ty * 4 + i;
            float bias = (b1 ? b1[n] : 0.f) + (b2 ? b2[n] : 0.f);
            C[m * ldc + n] = acc[i][j] + bias;
        }
}

// ---------------- WE[b][r][s] = Wih_ctx[r] . ENC_b[s]  (K=1024) ----------------
__global__ __launch_bounds__(256) void we_kernel(const float* __restrict__ Wih,
                                                 const float* __restrict__ ENC,
                                                 float* __restrict__ WE) {
    const float* A = Wih + 80;                          // [2048][1024], lda 1104
    const float* W = ENC + (size_t)blockIdx.z * 131072; // [128][1024]
    float* C = WE + (size_t)blockIdx.z * 262144;        // [2048][128]
    __shared__ float As[32][68];
    __shared__ float Ws[32][68];
    int tid = threadIdx.x;
    int tx = tid & 15, ty = tid >> 4;
    int n0 = blockIdx.x * 64, m0 = blockIdx.y * 64;
    float acc[4][4] = {};
    int r  = tid >> 3;
    int c4 = (tid & 7) * 4;
    for (int k0 = 0; k0 < 1024; k0 += 32) {
        float4 a0 = *(const float4*)&A[(size_t)(m0 + r) * 1104 + k0 + c4];
        float4 a1 = *(const float4*)&A[(size_t)(m0 + r + 32) * 1104 + k0 + c4];
        float4 w0 = *(const float4*)&W[(n0 + r) * 1024 + k0 + c4];
        float4 w1 = *(const float4*)&W[(n0 + r + 32) * 1024 + k0 + c4];
        As[c4 + 0][r] = a0.x; As[c4 + 1][r] = a0.y; As[c4 + 2][r] = a0.z; As[c4 + 3][r] = a0.w;
        As[c4 + 0][r + 32] = a1.x; As[c4 + 1][r + 32] = a1.y; As[c4 + 2][r + 32] = a1.z; As[c4 + 3][r + 32] = a1.w;
        Ws[c4 + 0][r] = w0.x; Ws[c4 + 1][r] = w0.y; Ws[c4 + 2][r] = w0.z; Ws[c4 + 3][r] = w0.w;
        Ws[c4 + 0][r + 32] = w1.x; Ws[c4 + 1][r + 32] = w1.y; Ws[c4 + 2][r + 32] = w1.z; Ws[c4 + 3][r + 32] = w1.w;
        __syncthreads();
#pragma unroll 8
        for (int kk = 0; kk < 32; ++kk) {
            float4 av = *(const float4*)&As[kk][ty * 4];
            float4 wv = *(const float4*)&Ws[kk][tx * 4];
            acc[0][0] = fmaf(av.x, wv.x, acc[0][0]); acc[0][1] = fmaf(av.x, wv.y, acc[0][1]);
            acc[0][2] = fmaf(av.x, wv.z, acc[0][2]); acc[0][3] = fmaf(av.x, wv.w, acc[0][3]);
            acc[1][0] = fmaf(av.y, wv.x, acc[1][0]); acc[1][1] = fmaf(av.y, wv.y, acc[1][1]);
            acc[1][2] = fmaf(av.y, wv.z, acc[1][2]); acc[1][3] = fmaf(av.y, wv.w, acc[1][3]);
            acc[2][0] = fmaf(av.z, wv.x, acc[2][0]); acc[2][1] = fmaf(av.z, wv.y, acc[2][1]);
            acc[2][2] = fmaf(av.z, wv.z, acc[2][2]); acc[2][3] = fmaf(av.z, wv.w, acc[2][3]);
            acc[3][0] = fmaf(av.w, wv.x, acc[3][0]); acc[3][1] = fmaf(av.w, wv.y, acc[3][1]);
            acc[3][2] = fmaf(av.w, wv.z, acc[3][2]); acc[3][3] = fmaf(av.w, wv.w, acc[3][3]);
        }
        __syncthreads();
    }
#pragma unroll
    for (int i = 0; i < 4; ++i)
#pragma unroll
        for (int j = 0; j < 4; ++j)
            C[(size_t)(m0 + ty * 4 + i) * 128 + n0 + tx * 4 + j] = acc[i][j];
}

// ---------------- WH2 = dec_Whh + Wih[:,:80] @ mel_W ----------------
__global__ __launch_bounds__(256) void wh2_kernel(const float* __restrict__ Wih,
                                                  const float* __restrict__ Whh,
                                                  const float* __restrict__ melW,
                                                  float* __restrict__ WH2) {
    int wg = blockIdx.x;          // 4096 WGs: r = wg>>1, k-half = wg&1
    int tid = threadIdx.x;
    int r = wg >> 1;
    int k = (wg & 1) * 256 + tid;
    __shared__ float wrow[80];
    if (tid < 80) wrow[tid] = Wih[(size_t)r * 1104 + tid];
    __syncthreads();
    float acc = Whh[(size_t)r * 512 + k];
#pragma unroll 8
    for (int m = 0; m < 80; ++m)
        acc = fmaf(wrow[m], melW[m * 512 + k], acc);
    WH2[(size_t)r * 512 + k] = acc;
}

// ---------------- biasA = bih+bhh ; biasB = biasA + Wih[:,:80].mel_b ----------------
__global__ __launch_bounds__(256) void bias_kernel(const float* __restrict__ Wih,
                                                   const float* __restrict__ bih,
                                                   const float* __restrict__ bhh,
                                                   const float* __restrict__ melb,
                                                   float* __restrict__ BA,
                                                   float* __restrict__ BB) {
    int r = blockIdx.x * 256 + threadIdx.x;
    float a = bih[r] + bhh[r];
    float b2 = 0.f;
#pragma unroll 8
    for (int m = 0; m < 80; ++m)
        b2 = fmaf(Wih[(size_t)r * 1104 + m], melb[m], b2);
    BA[r] = a;
    BB[r] = a + b2;
}

// ---------------- per-(dir,batch) LSTM: slice-major (r8) + vec staging ----------------
__global__ __launch_bounds__(256) void lstm_kernel(const float* __restrict__ GXf,
                                                   const float* __restrict__ GXb,
                                                   const float* __restrict__ Whh_f,
                                                   const float* __restrict__ Whh_b,
                                                   float* __restrict__ Hout,
                                                   float* __restrict__ hstate,
                                                   unsigned* __restrict__ flagsL) {
    int wg  = blockIdx.x;
    int s   = wg & 7;
    int g16 = wg >> 3;        // 0..15
    int dir = g16 >> 3;
    int b   = g16 & 7;
    const float* GX  = dir ? GXb : GXf;
    const float* Whh = dir ? Whh_b : Whh_f;
    float* hs = hstate + g16 * 1024;         // [2][512]
    unsigned* fg = flagsL + g16 * 128;       // 8 flag lines

    int tid = threadIdx.x;
    int g = tid >> 6, c = tid & 63;
    int col = s * 64 + c;
    int grow = g * 512 + col;
    const float* wr = Whh + (size_t)grow * 512;

    __shared__ float hsh[512];
    __shared__ float gvL[4][64];

    float cst = 0.f;    // cell state (tid<64: col = s*64+tid)

    for (int t = 0; t < 128; ++t) {
        poll_flags(fg, 8, (unsigned)t);
        if (tid < 128) {
            float4 v = agr_f4(hs + (t & 1) * 512 + tid * 4);
            *(float4*)&hsh[tid * 4] = v;
        }
        __syncthreads();

        int st = dir ? (127 - t) : t;
        float acc = GX[((size_t)b * S_ + st) * G_ + grow];
        float a0 = 0.f, a1 = 0.f, a2 = 0.f, a3 = 0.f;
#pragma unroll 8
        for (int k = 0; k < 512; k += 4) {
            float4 wv = *(const float4*)(wr + k);
            float4 hv = *(const float4*)&hsh[k];
            a0 = fmaf(wv.x, hv.x, a0); a1 = fmaf(wv.y, hv.y, a1);
            a2 = fmaf(wv.z, hv.z, a2); a3 = fmaf(wv.w, hv.w, a3);
        }
        gvL[g][c] = acc + (a0 + a1) + (a2 + a3);
        __syncthreads();

        float h2 = 0.f;
        if (tid < 64) {
            float gi = gvL[0][tid], gf = gvL[1][tid];
            float gg = gvL[2][tid], go = gvL[3][tid];
            float c2 = sigm_f(gf) * cst + sigm_f(gi) * tanh_f(gg);
            h2 = sigm_f(go) * tanh_f(c2);
            cst = c2;
            agw_f(hs + ((t & 1) ^ 1) * 512 + s * 64 + tid, h2);
        }
        set_flag(fg + s * 16, (unsigned)(t + 1));
        if (tid < 64)
            Hout[((size_t)b * S_ + st) * 1024 + dir * 512 + s * 64 + tid] = h2;
    }
}

// ---------------- decoder: folded gates (WH2/WE), 136 WGs ----------------
// gate WG: wg = b*16+s -> XCD s%8: slice s rows (cols [s*32,(s+1)*32) x 4 gates),
// streams WH2 slice (256KB) + WE slice (64KB) + W_h slice (64KB) — L2-hot.
// attn WG: wg = 128+b -> XCD b: scores+softmax -> att; mel (off-path) -> out.
// Per step: fC (h ready, DH ping-pong) -> gates{hW slice -> fA; WH2.h -> reg}
// -> attn{scores,softmax -> att, fB} -> gates{WE.att + cell -> h, fC}.
__global__ __launch_bounds__(256) void decoder_kernel(float* __restrict__ ws,
                                                      const float* __restrict__ attn_W,
                                                      const float* __restrict__ attn_v,
                                                      const float* __restrict__ mel_W,
                                                      const float* __restrict__ mel_b,
                                                      float* __restrict__ out, int T,
                                                      unsigned* __restrict__ flags) {
    float* ENCP = ws + OFF_ENCP;
    float* DH   = ws + OFF_DH;    // [2][8][512]
    float* ATT  = ws + OFF_ATT;   // [8][128]
    float* HW   = ws + OFF_HW;    // [8][512]
    const float* WE  = ws + OFF_WE;
    const float* WH2 = ws + OFF_WH2;
    const float* BA  = ws + OFF_BA;
    const float* BB  = ws + OFF_BB;

    int wg  = blockIdx.x;
    int tid = threadIdx.x;

    if (wg < 128) {
        // ================= gate WG (slice s, batch b) =================
        int s = wg & 15;
        int b = wg >> 4;
        unsigned* fC = flags + b * 1024;
        unsigned* fA = fC + 16 * 16;
        unsigned* fB = fC + 32 * 16;

        int r   = tid >> 1;                 // local row 0..127
        int half = tid & 1;
        int grow = (r >> 5) * 512 + s * 32 + (r & 31);
        const float* wh2_half = WH2 + (size_t)grow * 512 + half * 256;
        const float* we_row   = WE + ((size_t)b * 2048 + grow) * 128 + half * 64;
        float bias_a = (half == 0) ? BA[grow] : 0.f;
        float bias_b = (half == 0) ? BB[grow] : 0.f;
        // hW mapping (conflict-free broadcast): r2 = tid&31, oct = tid>>5
        int r2 = tid & 31, oct = tid >> 5;
        const float* wh_row = attn_W + (size_t)(s * 32 + r2) * 1536 + oct * 64;

        __shared__ float hsh[512];
        __shared__ float hwred[32][9];
        __shared__ float gBx[128][2];
        __shared__ float gv[128];
        __shared__ float attL[128];

        float cst = 0.f;   // tid<32: col = s*32+tid

        for (int t = 0; t < T; ++t) {
            // ---- phase A: stage h_t; hW slice -> fA; WH2.h partial -> reg ----
            poll_flags(fC, 16, (unsigned)t);
            const float* DHr = DH + (t & 1) * 4096 + b * 512;
            if (tid < 128) {
                float4 v = agr_f4(DHr + tid * 4);
                *(float4*)&hsh[tid * 4] = v;
            }
            __syncthreads();
            {
                const float* hp = hsh + oct * 64;
                float w = 0.f;
#pragma unroll 8
                for (int k = 0; k < 64; k += 4) {
                    float4 wv = *(const float4*)(wh_row + k);
                    float4 hv = *(const float4*)(hp + k);
                    w = fmaf(wv.x, hv.x, w); w = fmaf(wv.y, hv.y, w);
                    w = fmaf(wv.z, hv.z, w); w = fmaf(wv.w, hv.w, w);
                }
                hwred[r2][oct] = w;
            }
            __syncthreads();
            if (tid < 32) {
                float hw = hwred[tid][0] + hwred[tid][1] + hwred[tid][2] + hwred[tid][3]
                         + hwred[tid][4] + hwred[tid][5] + hwred[tid][6] + hwred[tid][7];
                agw_f(HW + b * 512 + s * 32 + tid, hw);
            }
            set_flag(fA + s * 16, (unsigned)(t + 1));

            // WH2.h partial (overlaps attention; stays in register)
            float wpart = (t == 0) ? bias_a : bias_b;
            {
                const float* hp = hsh + half * 256;
                float a0 = 0.f, a1 = 0.f, a2 = 0.f, a3 = 0.f;
#pragma unroll 8
                for (int k = 0; k < 256; k += 4) {
                    float4 wv = *(const float4*)(wh2_half + k);
                    float4 hv = *(const float4*)(hp + k);
                    a0 = fmaf(wv.x, hv.x, a0); a1 = fmaf(wv.y, hv.y, a1);
                    a2 = fmaf(wv.z, hv.z, a2); a3 = fmaf(wv.w, hv.w, a3);
                }
                wpart += (a0 + a1) + (a2 + a3);
            }

            // ---- phase B: WE.att + cell ----
            poll_flags(fB, 1, (unsigned)(t + 1));
            if (tid < 32) {
                float4 v = agr_f4(ATT + b * 128 + tid * 4);
                *(float4*)&attL[tid * 4] = v;
            }
            __syncthreads();
            {
                const float* ap = attL + half * 64;
                float a0 = 0.f, a1 = 0.f, a2 = 0.f, a3 = 0.f;
#pragma unroll 8
                for (int k = 0; k < 64; k += 4) {
                    float4 wv = *(const float4*)(we_row + k);
                    a0 = fmaf(wv.x, ap[k + 0], a0); a1 = fmaf(wv.y, ap[k + 1], a1);
                    a2 = fmaf(wv.z, ap[k + 2], a2); a3 = fmaf(wv.w, ap[k + 3], a3);
                }
                gBx[r][half] = wpart + (a0 + a1) + (a2 + a3);
            }
            __syncthreads();
            if (tid < 128)
                gv[tid] = gBx[tid][0] + gBx[tid][1];
            __syncthreads();
            if (tid < 32) {
                float gi = gv[tid], gf = gv[32 + tid], gg = gv[64 + tid], go = gv[96 + tid];
                float c2 = sigm_f(gf) * cst + sigm_f(gi) * tanh_f(gg);
                float h2 = sigm_f(go) * tanh_f(c2);
                cst = c2;
                agw_f(DH + ((t + 1) & 1) * 4096 + b * 512 + s * 32 + tid, h2);
            }
            set_flag(fC + s * 16, (unsigned)(t + 1));
        }
    } else {
        // ================= attention WG (batch b) =================
        int b = wg - 128;
        unsigned* fC = flags + b * 1024;
        unsigned* fA = fC + 16 * 16;
        unsigned* fB = fC + 32 * 16;

        __shared__ float hw2[512];
        __shared__ float dh2[512];
        __shared__ float scred[128][2];
        __shared__ float red[128];
        __shared__ float att[128];
        __shared__ float melp[80][2];

        int r = tid >> 1, half = tid & 1;

        for (int t = 0; t < T; ++t) {
            poll_flags(fA, 16, (unsigned)(t + 1));
            if (tid < 128) {
                float4 v = agr_f4(HW + b * 512 + tid * 4);
                *(float4*)&hw2[tid * 4] = v;
            }
            __syncthreads();

            // scores: sI = tid&127, k-half = tid>>7
            {
                int sI = tid & 127, kh = tid >> 7;
                const float* ep = ENCP + ((size_t)b * S_ + sI) * 512 + kh * 256;
                const float* hp = hw2 + kh * 256;
                const float* vv = attn_v + kh * 256;
                float a0 = 0.f, a1 = 0.f, a2 = 0.f, a3 = 0.f;
#pragma unroll 4
                for (int k = 0; k < 256; k += 4) {
                    float4 e4 = *(const float4*)(ep + k);
                    float4 h4 = *(const float4*)(hp + k);
                    float4 v4 = *(const float4*)(vv + k);
                    a0 = fmaf(tanh_f(e4.x + h4.x), v4.x, a0);
                    a1 = fmaf(tanh_f(e4.y + h4.y), v4.y, a1);
                    a2 = fmaf(tanh_f(e4.z + h4.z), v4.z, a2);
                    a3 = fmaf(tanh_f(e4.w + h4.w), v4.w, a3);
                }
                scred[sI][kh] = (a0 + a1) + (a2 + a3);
            }
            __syncthreads();

            float sc = 0.f;
            if (tid < 128) {
                sc = scred[tid][0] + scred[tid][1];
                red[tid] = sc;
            }
            __syncthreads();
            for (int off = 64; off >= 1; off >>= 1) {
                if (tid < off) red[tid] = fmaxf(red[tid], red[tid + off]);
                __syncthreads();
            }
            float mx = red[0];
            __syncthreads();
            if (tid < 128) {
                float e = __expf(sc - mx);
                att[tid] = e;
                red[tid] = e;
            }
            __syncthreads();
            if (tid < 64) red[tid] += red[tid + 64];
            __syncthreads();
            for (int off = 32; off >= 1; off >>= 1) {
                if (tid < off) red[tid] += red[tid + off];
                __syncthreads();
            }
            float inv = 1.f / red[0];
            if (tid < 128)
                agw_f(ATT + b * 128 + tid, att[tid] * inv);
            set_flag(fB, (unsigned)(t + 1));

            // ---- off-critical-path: mel from h_t -> out[t-1] ----
            if (t > 0) {
                if (tid < 128) {
                    float4 v = agr_f4(DH + (t & 1) * 4096 + b * 512 + tid * 4);
                    *(float4*)&dh2[tid * 4] = v;
                }
                __syncthreads();
                if (tid < 160) {
                    const float* wp = mel_W + (size_t)r * 512 + half * 256;
                    const float* hp = dh2 + half * 256;
                    float a0 = 0.f, a1 = 0.f, a2 = 0.f, a3 = 0.f;
#pragma unroll 8
                    for (int k = 0; k < 256; k += 4) {
                        float4 wv = *(const float4*)(wp + k);
                        float4 hv = *(const float4*)(hp + k);
                        a0 = fmaf(wv.x, hv.x, a0); a1 = fmaf(wv.y, hv.y, a1);
                        a2 = fmaf(wv.z, hv.z, a2); a3 = fmaf(wv.w, hv.w, a3);
                    }
                    melp[r][half] = (a0 + a1) + (a2 + a3);
                }
                __syncthreads();
                if (tid < 80)
                    out[b * MEL_ * T + tid * T + (t - 1)] = melp[tid][0] + melp[tid][1] + mel_b[tid];
            }
        }

        // epilogue: final mel from h_T -> out[T-1]
        poll_flags(fC, 16, (unsigned)T);
        if (tid < 128) {
            float4 v = agr_f4(DH + (T & 1) * 4096 + b * 512 + tid * 4);
            *(float4*)&dh2[tid * 4] = v;
        }
        __syncthreads();
        if (tid < 160) {
            const float* wp = mel_W + (size_t)r * 512 + half * 256;
            const float* hp = dh2 + half * 256;
            float a0 = 0.f, a1 = 0.f, a2 = 0.f, a3 = 0.f;
#pragma unroll 8
            for (int k = 0; k < 256; k += 4) {
                float4 wv = *(const float4*)(wp + k);
                float4 hv = *(const float4*)(hp + k);
                a0 = fmaf(wv.x, hv.x, a0); a1 = fmaf(wv.y, hv.y, a1);
                a2 = fmaf(wv.z, hv.z, a2); a3 = fmaf(wv.w, hv.w, a3);
            }
            melp[r][half] = (a0 + a1) + (a2 + a3);
        }
        __syncthreads();
        if (tid < 80)
            out[b * MEL_ * T + tid * T + (T - 1)] = melp[tid][0] + melp[tid][1] + mel_b[tid];
    }
}

// ---------------- host launch ----------------
extern "C" void kernel_launch(void* const* d_in, const int* in_sizes, int n_in,
                              void* d_out, int out_size, void* d_ws, size_t ws_size,
                              hipStream_t stream) {
    const int*   text  = (const int*)d_in[0];
    const float* emb   = (const float*)d_in[2];
    const float* Wih00 = (const float*)d_in[3];
    const float* Whh00 = (const float*)d_in[4];
    const float* bih00 = (const float*)d_in[5];
    const float* bhh00 = (const float*)d_in[6];
    const float* Wih01 = (const float*)d_in[7];
    const float* Whh01 = (const float*)d_in[8];
    const float* bih01 = (const float*)d_in[9];
    const float* bhh01 = (const float*)d_in[10];
    const float* Wih10 = (const float*)d_in[11];
    const float* Whh10 = (const float*)d_in[12];
    const float* bih10 = (const float*)d_in[13];
    const float* bhh10 = (const float*)d_in[14];
    const float* Wih11 = (const float*)d_in[15];
    const float* Whh11 = (const float*)d_in[16];
    const float* bih11 = (const float*)d_in[17];
    const float* bhh11 = (const float*)d_in[18];
    const float* attn_W = (const float*)d_in[19];
    const float* attn_b = (const float*)d_in[20];
    const float* attn_v = (const float*)d_in[21];
    const float* dec_Wih = (const float*)d_in[22];
    const float* dec_Whh = (const float*)d_in[23];
    const float* dec_bih = (const float*)d_in[24];
    const float* dec_bhh = (const float*)d_in[25];
    const float* mel_W = (const float*)d_in[26];
    const float* mel_b = (const float*)d_in[27];

    float* ws = (float*)d_ws;
    unsigned* flags = (unsigned*)d_ws;
    float* out = (float*)d_out;
    int T = out_size / (B_ * MEL_);   // 200

    // zero flags + recurrent state
    zero_kernel<<<ZERO_WORDS / 256, 256, 0, stream>>>(ws);

    // embedding
    embed_kernel<<<512, 256, 0, stream>>>(text, emb, ws + OFF_X0);

    // layer0 input projections (bias folded: bih + bhh)
    gemm_f32<<<dim3(32, 16), 256, 0, stream>>>(ws + OFF_X0, 512, Wih00, 512,
                                               bih00, bhh00, ws + OFF_GX0F, 2048, 512);
    gemm_f32<<<dim3(32, 16), 256, 0, stream>>>(ws + OFF_X0, 512, Wih01, 512,
                                               bih01, bhh01, ws + OFF_GX0B, 2048, 512);
    // layer0 recurrence
    lstm_kernel<<<128, 256, 0, stream>>>(ws + OFF_GX0F, ws + OFF_GX0B, Whh00, Whh01,
                                         ws + OFF_H0, ws + OFF_H0S, flags + FLG_L0);
    // decoder weight folds (GX0B is dead now)
    wh2_kernel<<<4096, 256, 0, stream>>>(dec_Wih, dec_Whh, mel_W, ws + OFF_WH2);
    bias_kernel<<<8, 256, 0, stream>>>(dec_Wih, dec_bih, dec_bhh, mel_b,
                                       ws + OFF_BA, ws + OFF_BB);
    // layer1 input projections
    gemm_f32<<<dim3(32, 16), 256, 0, stream>>>(ws + OFF_H0, 1024, Wih10, 1024,
                                               bih10, bhh10, ws + OFF_GX1F, 2048, 1024);
    gemm_f32<<<dim3(32, 16), 256, 0, stream>>>(ws + OFF_H0, 1024, Wih11, 1024,
                                               bih11, bhh11, ws + OFF_GX1B, 2048, 1024);
    // layer1 recurrence -> enc
    lstm_kernel<<<128, 256, 0, stream>>>(ws + OFF_GX1F, ws + OFF_GX1B, Whh10, Whh11,
                                         ws + OFF_ENC, ws + OFF_H1S, flags + FLG_L1);
    // enc_part = enc @ W_e^T + attn_b
    gemm_f32<<<dim3(8, 16), 256, 0, stream>>>(ws + OFF_ENC, 1024, attn_W + 512, 1536,
                                              attn_b, nullptr, ws + OFF_ENCP, 512, 1024);
    // WE[b] = Wih_ctx @ ENC_b^T (GX0F is dead now)
    we_kernel<<<dim3(2, 32, 8), 256, 0, stream>>>(dec_Wih, ws + OFF_ENC, ws + OFF_WE);
    // decoder: folded gates, 3 light edges/step
    decoder_kernel<<<136, 256, 0, stream>>>(ws, attn_W, attn_v, mel_W, mel_b, out, T,
                                            flags + FLG_DEC);
}